// Round 8
// baseline (242.203 us; speedup 1.0000x reference)
//
#include <hip/hip_runtime.h>
#include <math.h>

#define BSZ   2
#define TSEQ  2048
#define CDIM  1024
#define NHEAD 16
#define HDIM  64
#define BT    (BSZ*TSEQ)
#define NQKV  1152   // 1024 q + 64 k + 64 v

typedef __attribute__((ext_vector_type(8))) short short8;
typedef __attribute__((ext_vector_type(4))) float f32x4;
typedef unsigned short u16;
typedef unsigned int   u32;

__device__ __forceinline__ u16 f2b(float f) {
    union { float f; u32 u; } c; c.f = f;
    u32 u = c.u;
    u += 0x7fffu + ((u >> 16) & 1u);   // round-nearest-even
    return (u16)(u >> 16);
}
__device__ __forceinline__ u32 pack2(float lo, float hi) {
    return (u32)f2b(lo) | ((u32)f2b(hi) << 16);
}

// async global->LDS, 16B per lane. LDS dest must be wave-uniform base + lane*16.
__device__ __forceinline__ void async_copy16(const void* g, void* l) {
    __builtin_amdgcn_global_load_lds(
        (__attribute__((address_space(1))) const void*)g,
        (__attribute__((address_space(3))) void*)l,
        16, 0, 0);
}

// ---------------------------------------------------------------------------
// one 64x64 transpose+cast tile: W[K][Nw] fp32 -> Wt[nofs+n][K] bf16
// ---------------------------------------------------------------------------
__device__ __forceinline__ void transpose_tile(
    const float* __restrict__ W, u16* __restrict__ Wt,
    int K, int Nw, int nofs, int bx, int by, float (*T)[65])
{
    const int tid = threadIdx.x;
    const int k0 = by * 64, n0 = bx * 64;
    #pragma unroll
    for (int i = 0; i < 16; ++i) {
        int idx = i * 256 + tid, r = idx >> 6, c = idx & 63;
        T[r][c] = W[(size_t)(k0 + r) * Nw + n0 + c];
    }
    __syncthreads();
    #pragma unroll
    for (int i = 0; i < 16; ++i) {
        int idx = i * 256 + tid, rn = idx >> 6, ck = idx & 63;
        Wt[(size_t)(nofs + n0 + rn) * K + k0 + ck] = f2b(T[ck][rn]);
    }
}

// x-cast + all weight transposes + bias concat in ONE launch (blockIdx switch)
__global__ __launch_bounds__(256) void prep_kernel(
    const float* __restrict__ x,
    const float* __restrict__ Wq, const float* __restrict__ Wk,
    const float* __restrict__ Wv, const float* __restrict__ Wo,
    const float* __restrict__ bq, const float* __restrict__ bk,
    const float* __restrict__ bv,
    u16* __restrict__ xb,
    u16* __restrict__ Wqkvt, u16* __restrict__ Wot, float* __restrict__ bqkv)
{
    __shared__ float T[64][65];
    const int bid = blockIdx.x;
    if (bid < 4096) {
        // x -> bf16, 4 elems/thread (4096 blocks x 1024 elems)
        int i = bid * 256 + threadIdx.x;
        float4 f = ((const float4*)x)[i];
        u16* d = xb + (size_t)i * 4;
        d[0] = f2b(f.x); d[1] = f2b(f.y); d[2] = f2b(f.z); d[3] = f2b(f.w);
    } else if (bid < 4352) {
        int b2 = bid - 4096;
        transpose_tile(Wq, Wqkvt, 1024, 1024, 0, b2 & 15, b2 >> 4, T);
    } else if (bid < 4368) {
        transpose_tile(Wk, Wqkvt, 1024, 64, 1024, 0, bid - 4352, T);
    } else if (bid < 4384) {
        transpose_tile(Wv, Wqkvt, 1024, 64, 1088, 0, bid - 4368, T);
    } else if (bid < 4640) {
        int b2 = bid - 4384;
        transpose_tile(Wo, Wot, 1024, 1024, 0, b2 & 15, b2 >> 4, T);
    } else {
        for (int i = threadIdx.x; i < NQKV; i += 256)
            bqkv[i] = (i < 1024) ? bq[i] : (i < 1088 ? bk[i - 1024] : bv[i - 1088]);
    }
}

// ---------------------------------------------------------------------------
// 128x128 GEMM inner step: 8 ds_read_b128 + 16 MFMA (wave owns 64x64 = 4x4)
// ---------------------------------------------------------------------------
__device__ __forceinline__ void gemm_step128(
    const u16* __restrict__ As, const u16* __restrict__ Bs,
    int wm, int wn, int quad, int ln16, f32x4 (*acc)[4])
{
    short8 af[4], bf[4];
    #pragma unroll
    for (int mt = 0; mt < 4; ++mt)
        af[mt] = *(const short8*)&As[(((wm * 4 + mt) * 64) + quad * 16 + ln16) * 8];
    #pragma unroll
    for (int nt = 0; nt < 4; ++nt)
        bf[nt] = *(const short8*)&Bs[(((wn * 4 + nt) * 64) + quad * 16 + ln16) * 8];
    #pragma unroll
    for (int mt = 0; mt < 4; ++mt)
        #pragma unroll
        for (int nt = 0; nt < 4; ++nt)
            acc[mt][nt] = __builtin_amdgcn_mfma_f32_16x16x32_bf16(
                af[mt], bf[nt], acc[mt][nt], 0, 0, 0);
}

__device__ __forceinline__ void gemm_stage4(
    const u16* ag0, const u16* ag1, const u16* bg0, const u16* bg1,
    u16* al0, u16* al1, u16* bl0, u16* bl1)
{
    async_copy16(ag0, al0);
    async_copy16(ag1, al1);
    async_copy16(bg0, bl0);
    async_copy16(bg1, bl1);
}

// Counted-vmcnt 3-buffer 128x128 K-loop (T3/T4): 4 staging loads per tile,
// 2 tiles staged ahead (8 in flight); wait vmcnt(4) retires exactly the
// oldest tile's 4 loads before the barrier -> after the barrier tile k is
// collectively resident while the next tile's loads stay in flight. vmcnt
// reaches 0 only on the final iteration. K=1024, BK=32 -> 32 tiles = 3x10+2.
#define STAGE128(KOFS, I)                                                     \
    gemm_stage4(ag0 + (KOFS), ag1 + (KOFS), bg0 + (KOFS), bg1 + (KOFS),       \
                aLo##I, aHi##I, bLo##I, bHi##I)

#define GEMM128_PIPE_LOOP()                                                   \
    STAGE128(0, 0);                                                           \
    STAGE128(32, 1);                                                          \
    for (int k = 0; k < 30; k += 3) {                                         \
        const int kb = k * 32;                                                \
        asm volatile("s_waitcnt vmcnt(4)" ::: "memory");                      \
        __builtin_amdgcn_s_barrier();                                         \
        STAGE128(kb + 64, 2);                                                 \
        gemm_step128(AsC[0], BsC[0], wm, wn, quad, ln16, acc);                \
        asm volatile("s_waitcnt vmcnt(4)" ::: "memory");                      \
        __builtin_amdgcn_s_barrier();                                         \
        STAGE128(kb + 96, 0);                                                 \
        gemm_step128(AsC[1], BsC[1], wm, wn, quad, ln16, acc);                \
        asm volatile("s_waitcnt vmcnt(4)" ::: "memory");                      \
        __builtin_amdgcn_s_barrier();                                         \
        STAGE128(kb + 128, 1);                                                \
        gemm_step128(AsC[2], BsC[2], wm, wn, quad, ln16, acc);                \
    }                                                                         \
    asm volatile("s_waitcnt vmcnt(4)" ::: "memory");                          \
    __builtin_amdgcn_s_barrier();                                             \
    gemm_step128(AsC[0], BsC[0], wm, wn, quad, ln16, acc);                    \
    asm volatile("s_waitcnt vmcnt(0)" ::: "memory");                          \
    __builtin_amdgcn_s_barrier();                                             \
    gemm_step128(AsC[1], BsC[1], wm, wn, quad, ln16, acc);

#define GEMM128_SETUP(Aptr, Btptr, Kdim)                                      \
    const int tid  = threadIdx.x;                                             \
    const int wave = tid >> 6, lane = tid & 63;                               \
    const int ln16 = lane & 15, quad = lane >> 4;                             \
    const int wm = wave >> 1, wn = wave & 1;                                  \
    const int m0 = blockIdx.y * 128, n0 = blockIdx.x * 128;                   \
    const int c_row = (wave << 4) + ln16;                                     \
    const int c_k   = quad * 8;                                               \
    const u16* ag0 = &(Aptr) [(size_t)(m0 + c_row)       * (Kdim) + c_k];     \
    const u16* ag1 = &(Aptr) [(size_t)(m0 + 64 + c_row)  * (Kdim) + c_k];     \
    const u16* bg0 = &(Btptr)[(size_t)(n0 + c_row)       * (Kdim) + c_k];     \
    const u16* bg1 = &(Btptr)[(size_t)(n0 + 64 + c_row)  * (Kdim) + c_k];     \
    u16* aLo0 = &AsC[0][(size_t)wave * 512];                                  \
    u16* aLo1 = &AsC[1][(size_t)wave * 512];                                  \
    u16* aLo2 = &AsC[2][(size_t)wave * 512];                                  \
    u16* aHi0 = &AsC[0][(size_t)(wave + 4) * 512];                            \
    u16* aHi1 = &AsC[1][(size_t)(wave + 4) * 512];                            \
    u16* aHi2 = &AsC[2][(size_t)(wave + 4) * 512];                            \
    u16* bLo0 = &BsC[0][(size_t)wave * 512];                                  \
    u16* bLo1 = &BsC[1][(size_t)wave * 512];                                  \
    u16* bLo2 = &BsC[2][(size_t)wave * 512];                                  \
    u16* bHi0 = &BsC[0][(size_t)(wave + 4) * 512];                            \
    u16* bHi1 = &BsC[1][(size_t)(wave + 4) * 512];                            \
    u16* bHi2 = &BsC[2][(size_t)(wave + 4) * 512];                            \
    f32x4 acc[4][4];                                                          \
    _Pragma("unroll")                                                         \
    for (int i = 0; i < 4; ++i)                                               \
        _Pragma("unroll")                                                     \
        for (int j = 0; j < 4; ++j) acc[i][j] = (f32x4){0.f, 0.f, 0.f, 0.f};

// ---------------------------------------------------------------------------
// Fused qkv projection: 128x128 tile, BK=32, 4 waves (2x2, 64x64 each),
// counted-vmcnt 3-buffer pipeline. Epilogue (R1-verified): RoPE q (pre-scaled
// 0.125*log2e so flash uses exp2), RoPE k, transpose v.
// ---------------------------------------------------------------------------
__global__ __launch_bounds__(256) void gemm_qkv_kernel(
    const u16* __restrict__ A, const u16* __restrict__ Bt,
    const float* __restrict__ bias,
    u16* __restrict__ qb, u16* __restrict__ kb, u16* __restrict__ vT)
{
    __shared__ __align__(16) u16 AsC[3][128 * 32];   // 24 KB
    __shared__ __align__(16) u16 BsC[3][128 * 32];   // 24 KB
    GEMM128_SETUP(A, Bt, CDIM);

    GEMM128_PIPE_LOOP();

    // ---- bias ----
    #pragma unroll
    for (int mt = 0; mt < 4; ++mt)
        #pragma unroll
        for (int nt = 0; nt < 4; ++nt) {
            float bb = bias[n0 + wn * 64 + nt * 16 + ln16];
            #pragma unroll
            for (int r = 0; r < 4; ++r) acc[mt][nt][r] += bb;
        }

    const int col0 = n0 + wn * 64;   // head-aligned category base
    if (col0 < 1024) {
        // ---- q: rope + (1/8)*log2e scale (flash uses exp2) -> qb ----
        const int hh = col0 >> 6;
        #pragma unroll
        for (int nt = 0; nt < 2; ++nt) {
            int j = nt * 16 + ln16;
            float fr = exp2f(-0.41524101186092029f * (float)j);  // 10000^(-j/32)
            #pragma unroll
            for (int mt = 0; mt < 4; ++mt)
                #pragma unroll
                for (int r = 0; r < 4; ++r) {
                    int m = m0 + wm * 64 + mt * 16 + quad * 4 + r;
                    float sn, cs;
                    __sincosf((float)(m & (TSEQ - 1)) * fr, &sn, &cs);
                    float t1 = acc[mt][nt][r], t2 = acc[mt][nt + 2][r];
                    u16* o = qb + (size_t)m * CDIM + hh * 64 + j;
                    o[0]  = f2b(fmaf(t1, cs,  t2 * sn) * 0.18033688011112043f);
                    o[32] = f2b(fmaf(t1, sn, -t2 * cs) * 0.18033688011112043f);
                }
        }
    } else if (wn == 0) {
        // ---- k: rope -> kb[bt][64] ----
        #pragma unroll
        for (int nt = 0; nt < 2; ++nt) {
            int j = nt * 16 + ln16;
            float fr = exp2f(-0.41524101186092029f * (float)j);
            #pragma unroll
            for (int mt = 0; mt < 4; ++mt)
                #pragma unroll
                for (int r = 0; r < 4; ++r) {
                    int m = m0 + wm * 64 + mt * 16 + quad * 4 + r;
                    float sn, cs;
                    __sincosf((float)(m & (TSEQ - 1)) * fr, &sn, &cs);
                    float t1 = acc[mt][nt][r], t2 = acc[mt][nt + 2][r];
                    u16* o = kb + (size_t)m * HDIM + j;
                    o[0]  = f2b(fmaf(t1, cs,  t2 * sn));
                    o[32] = f2b(fmaf(t1, sn, -t2 * cs));
                }
        }
    } else {
        // ---- v: transpose -> vT[b][d][T] (4 consecutive rows = 8B store) ----
        #pragma unroll
        for (int nt = 0; nt < 4; ++nt) {
            int d = nt * 16 + ln16;
            #pragma unroll
            for (int mt = 0; mt < 4; ++mt) {
                int mr = m0 + wm * 64 + mt * 16 + quad * 4;
                int b  = mr >> 11, tq = mr & (TSEQ - 1);
                uint2 val;
                val.x = pack2(acc[mt][nt][0], acc[mt][nt][1]);
                val.y = pack2(acc[mt][nt][2], acc[mt][nt][3]);
                *(uint2*)&vT[(size_t)(b * HDIM + d) * TSEQ + tq] = val;
            }
        }
    }
}

// ---------------------------------------------------------------------------
// Output projection: Y fp32 = A(bf16) @ Bt(bf16)^T + bias. 128x128 tile,
// BK=32, 4 waves (2x2), counted-vmcnt 3-buffer pipeline.
// ---------------------------------------------------------------------------
__global__ __launch_bounds__(256) void gemm_mfma_kernel(
    const u16* __restrict__ A, const u16* __restrict__ Bt,
    const float* __restrict__ bias, float* __restrict__ Y,
    int M, int N, int K)
{
    __shared__ __align__(16) u16 AsC[3][128 * 32];   // 24 KB
    __shared__ __align__(16) u16 BsC[3][128 * 32];   // 24 KB
    GEMM128_SETUP(A, Bt, K);

    GEMM128_PIPE_LOOP();

    #pragma unroll
    for (int mt = 0; mt < 4; ++mt)
        #pragma unroll
        for (int nt = 0; nt < 4; ++nt) {
            int n = n0 + wn * 64 + nt * 16 + ln16;
            float bb = bias[n];
            #pragma unroll
            for (int r = 0; r < 4; ++r) {
                int m = m0 + wm * 64 + mt * 16 + quad * 4 + r;
                Y[(size_t)m * N + n] = acc[mt][nt][r] + bb;
            }
        }
}

// ---------------------------------------------------------------------------
// Flash attention (R4 skeleton + V-direct-from-L2):
// QBLK=64, shift-free softmax, K double-buffered in LDS; V NO LONGER STAGED —
// V per batch is 256 KB (L2-resident; all 32 blocks of a batch share it), so
// each wave loads its 8 V fragments straight from vT at tile start and the
// QK^T+softmax work (~300-450 cyc) hides the ~200 cyc L2 latency
// (Common-mistake #7 / m169: V-staging at this size was pure overhead).
// Effects: LDS 49->33 KB = 4 blocks/CU (16 waves), V LDS reads (40% of LDS
// traffic) eliminated, staging loads per tile halved. Bit-identical output.
// P stored TRUNCATED (bits>>16); row-sum on the MFMA pipe via all-ones B
// operand reading the SAME truncated bf16 P as PV. q pre-scaled by
// 0.125*log2e -> e = exp2(s). __launch_bounds__(256,4) pins VGPR<=128 so the
// 4-block occupancy holds.
// ---------------------------------------------------------------------------
__device__ __forceinline__ void flash_stage_k(
    const u16* __restrict__ kb, int b, int kt, u16* __restrict__ Ksb,
    const int* row_c, const int* off_c, int c0)
{
    const size_t kt0 = (size_t)(b * TSEQ + kt * 64);
    #pragma unroll
    for (int hf = 0; hf < 2; ++hf) {
        int cc = c0 + hf * 256;
        async_copy16(kb + (kt0 + row_c[hf]) * HDIM + off_c[hf], Ksb + cc * 8);
    }
}

__device__ __forceinline__ void flash_tile(
    const u16* __restrict__ Ksb, const u16* __restrict__ vT,
    const u16* __restrict__ Qs, u16* __restrict__ Pw,
    int b, int kt, int wave, int ln16, int quad, bool diag,
    f32x4* lacc, f32x4* oacc)
{
    // ---- issue V fragment loads early (L2-hit; consumed by PV below) ----
    // mapping (chunk-layout inverse): vf(t,kk2) = vT[b*64 + t*16+ln16][kt*64 + kk2*32 + quad*8]
    short8 vreg[8];
    #pragma unroll
    for (int kk2 = 0; kk2 < 2; ++kk2)
        #pragma unroll
        for (int t = 0; t < 4; ++t)
            vreg[kk2 * 4 + t] = *(const short8*)&vT[
                (size_t)(b * HDIM + t * 16 + ln16) * TSEQ + kt * 64 + kk2 * 32 + quad * 8];

    // ---- S = Q.K^T ----
    f32x4 sv[4];
    #pragma unroll
    for (int t = 0; t < 4; ++t) sv[t] = (f32x4){0.f, 0.f, 0.f, 0.f};
    #pragma unroll
    for (int kk2 = 0; kk2 < 2; ++kk2) {
        short8 af = *(const short8*)&Qs[(wave * 128 + kk2 * 64 + quad * 16 + ln16) * 8];
        #pragma unroll
        for (int t = 0; t < 4; ++t) {
            short8 bf = *(const short8*)&Ksb[(t * 128 + kk2 * 64 + quad * 16 + ln16) * 8];
            sv[t] = __builtin_amdgcn_mfma_f32_16x16x32_bf16(af, bf, sv[t], 0, 0, 0);
        }
    }

    // ---- e = exp2(s') (0 if masked); truncated bf16 into Pw ----
    if (diag) {
        #pragma unroll
        for (int t = 0; t < 4; ++t) {
            int key = t * 16 + ln16;
            #pragma unroll
            for (int r = 0; r < 4; ++r) {
                float e = (key > wave * 16 + quad * 4 + r) ? 0.f : exp2f(sv[t][r]);
                Pw[(quad * 4 + r) * 72 + t * 16 + ln16] =
                    (u16)(__float_as_uint(e) >> 16);
            }
        }
    } else {
        #pragma unroll
        for (int t = 0; t < 4; ++t)
            #pragma unroll
            for (int r = 0; r < 4; ++r) {
                float e = exp2f(sv[t][r]);
                Pw[(quad * 4 + r) * 72 + t * 16 + ln16] =
                    (u16)(__float_as_uint(e) >> 16);
            }
    }

    // ---- O += P.V ; denominator via ones-column MFMA on same P ----
    const short8 ones = {0x3F80, 0x3F80, 0x3F80, 0x3F80,
                         0x3F80, 0x3F80, 0x3F80, 0x3F80};   // bf16 1.0
    #pragma unroll
    for (int kk2 = 0; kk2 < 2; ++kk2) {
        short8 pf = *(const short8*)&Pw[ln16 * 72 + kk2 * 32 + quad * 8];
        *lacc = __builtin_amdgcn_mfma_f32_16x16x32_bf16(pf, ones, *lacc, 0, 0, 0);
        #pragma unroll
        for (int t = 0; t < 4; ++t)
            oacc[t] = __builtin_amdgcn_mfma_f32_16x16x32_bf16(
                pf, vreg[kk2 * 4 + t], oacc[t], 0, 0, 0);
    }
}

__global__ __launch_bounds__(256, 4) void flash_mfma_kernel(
    const u16* __restrict__ qb, const u16* __restrict__ kb,
    const u16* __restrict__ vT, u16* __restrict__ o)
{
    const int id  = blockIdx.x;
    const int qt  = 31 - (id >> 5);   // longest blocks first (LPT)
    const int hb  = id & 31;
    const int h   = hb >> 1;
    const int b   = hb & 1;
    __shared__ __align__(16) u16 Qs [512 * 8];       // 8 KB
    __shared__ __align__(16) u16 Ks0[512 * 8];       // 8 KB  (double buffer)
    __shared__ __align__(16) u16 Ks1[512 * 8];       // 8 KB
    __shared__ __align__(16) u16 Ps[4 * 16 * 72];    // 9 KB, per-wave [16][72]

    const int tid  = threadIdx.x;
    const int wave = tid >> 6, lane = tid & 63;
    const int ln16 = lane & 15, quad = lane >> 4;

    const int c0 = tid;
    int row_c[2], off_c[2];
    #pragma unroll
    for (int hf = 0; hf < 2; ++hf) {
        int c = c0 + hf * 256;
        row_c[hf] = ((c >> 7) << 4) | (c & 15);
        off_c[hf] = ((c >> 6) & 1) * 32 + ((c >> 4) & 3) * 8;
    }

    u16* Pw = &Ps[wave * 16 * 72];

    // ---- stage Q + K tile 0 ----
    #pragma unroll
    for (int hf = 0; hf < 2; ++hf)
        async_copy16(
            qb + (size_t)(b * TSEQ + qt * 64 + row_c[hf]) * CDIM + h * HDIM + off_c[hf],
            Qs + (c0 + hf * 256) * 8);
    flash_stage_k(kb, b, 0, Ks0, row_c, off_c, c0);

    f32x4 lacc = (f32x4){0.f, 0.f, 0.f, 0.f};
    f32x4 oacc[4];
    #pragma unroll
    for (int t = 0; t < 4; ++t) oacc[t] = (f32x4){0.f, 0.f, 0.f, 0.f};

    int kt = 0;
    while (true) {
        __syncthreads();    // buf0 for kt ready; all waves done reading buf1
        if (kt < qt) flash_stage_k(kb, b, kt + 1, Ks1, row_c, off_c, c0);
        flash_tile(Ks0, vT, Qs, Pw, b, kt, wave, ln16, quad, kt == qt, &lacc, oacc);
        if (++kt > qt) break;
        __syncthreads();    // buf1 for kt ready; all waves done reading buf0
        if (kt < qt) flash_stage_k(kb, b, kt + 1, Ks0, row_c, off_c, c0);
        flash_tile(Ks1, vT, Qs, Pw, b, kt, wave, ln16, quad, kt == qt, &lacc, oacc);
        if (++kt > qt) break;
    }

    // ---- epilogue: denominators already fully reduced in lacc ----
    float inv[4];
    #pragma unroll
    for (int r = 0; r < 4; ++r) inv[r] = 1.0f / lacc[r];
    #pragma unroll
    for (int t = 0; t < 4; ++t) {
        #pragma unroll
        for (int r = 0; r < 4; ++r) {
            int row = qt * 64 + wave * 16 + quad * 4 + r;
            int d   = t * 16 + ln16;
            o[(size_t)(b * TSEQ + row) * CDIM + h * HDIM + d] = f2b(oacc[t][r] * inv[r]);
        }
    }
}

// ---------------------------------------------------------------------------
extern "C" void kernel_launch(void* const* d_in, const int* in_sizes, int n_in,
                              void* d_out, int out_size, void* d_ws, size_t ws_size,
                              hipStream_t stream)
{
    const float* x  = (const float*)d_in[0];
    const float* Wq = (const float*)d_in[1];
    const float* bq = (const float*)d_in[2];
    const float* Wk = (const float*)d_in[3];
    const float* bk = (const float*)d_in[4];
    const float* Wv = (const float*)d_in[5];
    const float* bv = (const float*)d_in[6];
    const float* Wo = (const float*)d_in[7];
    const float* bo = (const float*)d_in[8];
    float* out = (float*)d_out;

    const size_t MB = 1u << 20;
    char* w = (char*)d_ws;
    u16*   xb   = (u16*)(w);                   //  8 MB [BT][1024] bf16
    u16*   aob  = (u16*)(w);                   //  alias: xb dead after qkv GEMM
    u16*   qb   = (u16*)(w + 8 * MB);          //  8 MB [BT][1024] rope'd, scaled
    u16*   kb   = (u16*)(w + 16 * MB);         //  0.5 MB [BT][64]
    u16*   vT   = (u16*)(w + 16 * MB + 512 * 1024);   // 0.5 MB [B][64][T]
    u16*   Wqkvt= (u16*)(w + 17 * MB);         //  2.25 MB [1152][1024]
    u16*   Wot  = (u16*)(w + 20 * MB);         //  2 MB
    float* bqkv = (float*)(w + 22 * MB);       //  4.5 KB

    // 1) x-cast + weight transposes + bias concat, one launch
    prep_kernel<<<dim3(4641), dim3(256), 0, stream>>>(
        x, Wq, Wk, Wv, Wo, bq, bk, bv, xb, Wqkvt, Wot, bqkv);
    // 2) fused qkv projection + rope + v-transpose -> qb, kb, vT (bf16)
    gemm_qkv_kernel<<<dim3(NQKV / 128, BT / 128), dim3(256), 0, stream>>>(
        xb, Wqkvt, bqkv, qb, kb, vT);
    // 3) flash attention -> aob (overwrites dead xb)
    flash_mfma_kernel<<<dim3(32 * NHEAD * BSZ), dim3(256), 0, stream>>>(
        qb, kb, vT, aob);
    // 4) output projection
    gemm_mfma_kernel<<<dim3(CDIM / 128, BT / 128), dim3(256), 0, stream>>>(
        aob, Wot, bo, out, BT, CDIM, CDIM);
}

// Round 9
// 191.589 us; speedup vs baseline: 1.2642x; 1.2642x over previous
//
#include <hip/hip_runtime.h>
#include <math.h>

#define BSZ   2
#define TSEQ  2048
#define CDIM  1024
#define NHEAD 16
#define HDIM  64
#define BT    (BSZ*TSEQ)
#define NQKV  1152   // 1024 q + 64 k + 64 v

typedef __attribute__((ext_vector_type(8))) short short8;
typedef __attribute__((ext_vector_type(4))) float f32x4;
typedef unsigned short u16;
typedef unsigned int   u32;

__device__ __forceinline__ u16 f2b(float f) {
    union { float f; u32 u; } c; c.f = f;
    u32 u = c.u;
    u += 0x7fffu + ((u >> 16) & 1u);   // round-nearest-even
    return (u16)(u >> 16);
}
__device__ __forceinline__ u32 pack2(float lo, float hi) {
    return (u32)f2b(lo) | ((u32)f2b(hi) << 16);
}

// async global->LDS, 16B per lane. LDS dest must be wave-uniform base + lane*16.
__device__ __forceinline__ void async_copy16(const void* g, void* l) {
    __builtin_amdgcn_global_load_lds(
        (__attribute__((address_space(1))) const void*)g,
        (__attribute__((address_space(3))) void*)l,
        16, 0, 0);
}

// ---------------------------------------------------------------------------
// one 64x64 transpose+cast tile: W[K][Nw] fp32 -> Wt[nofs+n][K] bf16
// ---------------------------------------------------------------------------
__device__ __forceinline__ void transpose_tile(
    const float* __restrict__ W, u16* __restrict__ Wt,
    int K, int Nw, int nofs, int bx, int by, float (*T)[65])
{
    const int tid = threadIdx.x;
    const int k0 = by * 64, n0 = bx * 64;
    #pragma unroll
    for (int i = 0; i < 16; ++i) {
        int idx = i * 256 + tid, r = idx >> 6, c = idx & 63;
        T[r][c] = W[(size_t)(k0 + r) * Nw + n0 + c];
    }
    __syncthreads();
    #pragma unroll
    for (int i = 0; i < 16; ++i) {
        int idx = i * 256 + tid, rn = idx >> 6, ck = idx & 63;
        Wt[(size_t)(nofs + n0 + rn) * K + k0 + ck] = f2b(T[ck][rn]);
    }
}

// x-cast + all weight transposes + bias concat in ONE launch (blockIdx switch)
__global__ __launch_bounds__(256) void prep_kernel(
    const float* __restrict__ x,
    const float* __restrict__ Wq, const float* __restrict__ Wk,
    const float* __restrict__ Wv, const float* __restrict__ Wo,
    const float* __restrict__ bq, const float* __restrict__ bk,
    const float* __restrict__ bv,
    u16* __restrict__ xb,
    u16* __restrict__ Wqkvt, u16* __restrict__ Wot, float* __restrict__ bqkv)
{
    __shared__ float T[64][65];
    const int bid = blockIdx.x;
    if (bid < 4096) {
        // x -> bf16, 4 elems/thread (4096 blocks x 1024 elems)
        int i = bid * 256 + threadIdx.x;
        float4 f = ((const float4*)x)[i];
        u16* d = xb + (size_t)i * 4;
        d[0] = f2b(f.x); d[1] = f2b(f.y); d[2] = f2b(f.z); d[3] = f2b(f.w);
    } else if (bid < 4352) {
        int b2 = bid - 4096;
        transpose_tile(Wq, Wqkvt, 1024, 1024, 0, b2 & 15, b2 >> 4, T);
    } else if (bid < 4368) {
        transpose_tile(Wk, Wqkvt, 1024, 64, 1024, 0, bid - 4352, T);
    } else if (bid < 4384) {
        transpose_tile(Wv, Wqkvt, 1024, 64, 1088, 0, bid - 4368, T);
    } else if (bid < 4640) {
        int b2 = bid - 4384;
        transpose_tile(Wo, Wot, 1024, 1024, 0, b2 & 15, b2 >> 4, T);
    } else {
        for (int i = threadIdx.x; i < NQKV; i += 256)
            bqkv[i] = (i < 1024) ? bq[i] : (i < 1088 ? bk[i - 1024] : bv[i - 1088]);
    }
}

// ---------------------------------------------------------------------------
// 128x128 GEMM inner step: 8 ds_read_b128 + 16 MFMA (wave owns 64x64 = 4x4)
// ---------------------------------------------------------------------------
__device__ __forceinline__ void gemm_step128(
    const u16* __restrict__ As, const u16* __restrict__ Bs,
    int wm, int wn, int quad, int ln16, f32x4 (*acc)[4])
{
    short8 af[4], bf[4];
    #pragma unroll
    for (int mt = 0; mt < 4; ++mt)
        af[mt] = *(const short8*)&As[(((wm * 4 + mt) * 64) + quad * 16 + ln16) * 8];
    #pragma unroll
    for (int nt = 0; nt < 4; ++nt)
        bf[nt] = *(const short8*)&Bs[(((wn * 4 + nt) * 64) + quad * 16 + ln16) * 8];
    #pragma unroll
    for (int mt = 0; mt < 4; ++mt)
        #pragma unroll
        for (int nt = 0; nt < 4; ++nt)
            acc[mt][nt] = __builtin_amdgcn_mfma_f32_16x16x32_bf16(
                af[mt], bf[nt], acc[mt][nt], 0, 0, 0);
}

__device__ __forceinline__ void gemm_stage4(
    const u16* ag0, const u16* ag1, const u16* bg0, const u16* bg1,
    u16* al0, u16* al1, u16* bl0, u16* bl1)
{
    async_copy16(ag0, al0);
    async_copy16(ag1, al1);
    async_copy16(bg0, bl0);
    async_copy16(bg1, bl1);
}

// Counted-vmcnt 3-buffer 128x128 K-loop (T3/T4): 4 staging loads per tile,
// 2 tiles staged ahead (8 in flight); wait vmcnt(4) retires exactly the
// oldest tile's 4 loads before the barrier -> after the barrier tile k is
// collectively resident while the next tile's loads stay in flight. vmcnt
// reaches 0 only on the final iteration. K=1024, BK=32 -> 32 tiles = 3x10+2.
#define STAGE128(KOFS, I)                                                     \
    gemm_stage4(ag0 + (KOFS), ag1 + (KOFS), bg0 + (KOFS), bg1 + (KOFS),       \
                aLo##I, aHi##I, bLo##I, bHi##I)

#define GEMM128_PIPE_LOOP()                                                   \
    STAGE128(0, 0);                                                           \
    STAGE128(32, 1);                                                          \
    for (int k = 0; k < 30; k += 3) {                                         \
        const int kb = k * 32;                                                \
        asm volatile("s_waitcnt vmcnt(4)" ::: "memory");                      \
        __builtin_amdgcn_s_barrier();                                         \
        STAGE128(kb + 64, 2);                                                 \
        gemm_step128(AsC[0], BsC[0], wm, wn, quad, ln16, acc);                \
        asm volatile("s_waitcnt vmcnt(4)" ::: "memory");                      \
        __builtin_amdgcn_s_barrier();                                         \
        STAGE128(kb + 96, 0);                                                 \
        gemm_step128(AsC[1], BsC[1], wm, wn, quad, ln16, acc);                \
        asm volatile("s_waitcnt vmcnt(4)" ::: "memory");                      \
        __builtin_amdgcn_s_barrier();                                         \
        STAGE128(kb + 128, 1);                                                \
        gemm_step128(AsC[2], BsC[2], wm, wn, quad, ln16, acc);                \
    }                                                                         \
    asm volatile("s_waitcnt vmcnt(4)" ::: "memory");                          \
    __builtin_amdgcn_s_barrier();                                             \
    gemm_step128(AsC[0], BsC[0], wm, wn, quad, ln16, acc);                    \
    asm volatile("s_waitcnt vmcnt(0)" ::: "memory");                          \
    __builtin_amdgcn_s_barrier();                                             \
    gemm_step128(AsC[1], BsC[1], wm, wn, quad, ln16, acc);

#define GEMM128_SETUP(Aptr, Btptr, Kdim)                                      \
    const int tid  = threadIdx.x;                                             \
    const int wave = tid >> 6, lane = tid & 63;                               \
    const int ln16 = lane & 15, quad = lane >> 4;                             \
    const int wm = wave >> 1, wn = wave & 1;                                  \
    const int m0 = blockIdx.y * 128, n0 = blockIdx.x * 128;                   \
    const int c_row = (wave << 4) + ln16;                                     \
    const int c_k   = quad * 8;                                               \
    const u16* ag0 = &(Aptr) [(size_t)(m0 + c_row)       * (Kdim) + c_k];     \
    const u16* ag1 = &(Aptr) [(size_t)(m0 + 64 + c_row)  * (Kdim) + c_k];     \
    const u16* bg0 = &(Btptr)[(size_t)(n0 + c_row)       * (Kdim) + c_k];     \
    const u16* bg1 = &(Btptr)[(size_t)(n0 + 64 + c_row)  * (Kdim) + c_k];     \
    u16* aLo0 = &AsC[0][(size_t)wave * 512];                                  \
    u16* aLo1 = &AsC[1][(size_t)wave * 512];                                  \
    u16* aLo2 = &AsC[2][(size_t)wave * 512];                                  \
    u16* aHi0 = &AsC[0][(size_t)(wave + 4) * 512];                            \
    u16* aHi1 = &AsC[1][(size_t)(wave + 4) * 512];                            \
    u16* aHi2 = &AsC[2][(size_t)(wave + 4) * 512];                            \
    u16* bLo0 = &BsC[0][(size_t)wave * 512];                                  \
    u16* bLo1 = &BsC[1][(size_t)wave * 512];                                  \
    u16* bLo2 = &BsC[2][(size_t)wave * 512];                                  \
    u16* bHi0 = &BsC[0][(size_t)(wave + 4) * 512];                            \
    u16* bHi1 = &BsC[1][(size_t)(wave + 4) * 512];                            \
    u16* bHi2 = &BsC[2][(size_t)(wave + 4) * 512];                            \
    f32x4 acc[4][4];                                                          \
    _Pragma("unroll")                                                         \
    for (int i = 0; i < 4; ++i)                                               \
        _Pragma("unroll")                                                     \
        for (int j = 0; j < 4; ++j) acc[i][j] = (f32x4){0.f, 0.f, 0.f, 0.f};

// ---------------------------------------------------------------------------
// Fused qkv projection: 128x128 tile, BK=32, 4 waves (2x2, 64x64 each),
// counted-vmcnt 3-buffer pipeline. Epilogue (R1-verified): RoPE q (pre-scaled
// 0.125*log2e so flash uses exp2), RoPE k, transpose v.
// ---------------------------------------------------------------------------
__global__ __launch_bounds__(256) void gemm_qkv_kernel(
    const u16* __restrict__ A, const u16* __restrict__ Bt,
    const float* __restrict__ bias,
    u16* __restrict__ qb, u16* __restrict__ kb, u16* __restrict__ vT)
{
    __shared__ __align__(16) u16 AsC[3][128 * 32];   // 24 KB
    __shared__ __align__(16) u16 BsC[3][128 * 32];   // 24 KB
    GEMM128_SETUP(A, Bt, CDIM);

    GEMM128_PIPE_LOOP();

    // ---- bias ----
    #pragma unroll
    for (int mt = 0; mt < 4; ++mt)
        #pragma unroll
        for (int nt = 0; nt < 4; ++nt) {
            float bb = bias[n0 + wn * 64 + nt * 16 + ln16];
            #pragma unroll
            for (int r = 0; r < 4; ++r) acc[mt][nt][r] += bb;
        }

    const int col0 = n0 + wn * 64;   // head-aligned category base
    if (col0 < 1024) {
        // ---- q: rope + (1/8)*log2e scale (flash uses exp2) -> qb ----
        const int hh = col0 >> 6;
        #pragma unroll
        for (int nt = 0; nt < 2; ++nt) {
            int j = nt * 16 + ln16;
            float fr = exp2f(-0.41524101186092029f * (float)j);  // 10000^(-j/32)
            #pragma unroll
            for (int mt = 0; mt < 4; ++mt)
                #pragma unroll
                for (int r = 0; r < 4; ++r) {
                    int m = m0 + wm * 64 + mt * 16 + quad * 4 + r;
                    float sn, cs;
                    __sincosf((float)(m & (TSEQ - 1)) * fr, &sn, &cs);
                    float t1 = acc[mt][nt][r], t2 = acc[mt][nt + 2][r];
                    u16* o = qb + (size_t)m * CDIM + hh * 64 + j;
                    o[0]  = f2b(fmaf(t1, cs,  t2 * sn) * 0.18033688011112043f);
                    o[32] = f2b(fmaf(t1, sn, -t2 * cs) * 0.18033688011112043f);
                }
        }
    } else if (wn == 0) {
        // ---- k: rope -> kb[bt][64] ----
        #pragma unroll
        for (int nt = 0; nt < 2; ++nt) {
            int j = nt * 16 + ln16;
            float fr = exp2f(-0.41524101186092029f * (float)j);
            #pragma unroll
            for (int mt = 0; mt < 4; ++mt)
                #pragma unroll
                for (int r = 0; r < 4; ++r) {
                    int m = m0 + wm * 64 + mt * 16 + quad * 4 + r;
                    float sn, cs;
                    __sincosf((float)(m & (TSEQ - 1)) * fr, &sn, &cs);
                    float t1 = acc[mt][nt][r], t2 = acc[mt][nt + 2][r];
                    u16* o = kb + (size_t)m * HDIM + j;
                    o[0]  = f2b(fmaf(t1, cs,  t2 * sn));
                    o[32] = f2b(fmaf(t1, sn, -t2 * cs));
                }
        }
    } else {
        // ---- v: transpose -> vT[b][d][T] (4 consecutive rows = 8B store) ----
        #pragma unroll
        for (int nt = 0; nt < 4; ++nt) {
            int d = nt * 16 + ln16;
            #pragma unroll
            for (int mt = 0; mt < 4; ++mt) {
                int mr = m0 + wm * 64 + mt * 16 + quad * 4;
                int b  = mr >> 11, tq = mr & (TSEQ - 1);
                uint2 val;
                val.x = pack2(acc[mt][nt][0], acc[mt][nt][1]);
                val.y = pack2(acc[mt][nt][2], acc[mt][nt][3]);
                *(uint2*)&vT[(size_t)(b * HDIM + d) * TSEQ + tq] = val;
            }
        }
    }
}

// ---------------------------------------------------------------------------
// Output projection: Y fp32 = A(bf16) @ Bt(bf16)^T + bias. 128x128 tile,
// BK=32, 4 waves (2x2), counted-vmcnt 3-buffer pipeline.
// ---------------------------------------------------------------------------
__global__ __launch_bounds__(256) void gemm_mfma_kernel(
    const u16* __restrict__ A, const u16* __restrict__ Bt,
    const float* __restrict__ bias, float* __restrict__ Y,
    int M, int N, int K)
{
    __shared__ __align__(16) u16 AsC[3][128 * 32];   // 24 KB
    __shared__ __align__(16) u16 BsC[3][128 * 32];   // 24 KB
    GEMM128_SETUP(A, Bt, K);

    GEMM128_PIPE_LOOP();

    #pragma unroll
    for (int mt = 0; mt < 4; ++mt)
        #pragma unroll
        for (int nt = 0; nt < 4; ++nt) {
            int n = n0 + wn * 64 + nt * 16 + ln16;
            float bb = bias[n];
            #pragma unroll
            for (int r = 0; r < 4; ++r) {
                int m = m0 + wm * 64 + mt * 16 + quad * 4 + r;
                Y[(size_t)m * N + n] = acc[mt][nt][r] + bb;
            }
        }
}

// ---------------------------------------------------------------------------
// Flash attention (R4 measured-best 47.1us, reverted verbatim after R8's
// V-direct regression — the vT chunk staging IS the coalescing transform;
// direct per-lane reads of transposed V stride 4KB/lane and fragment into
// 16 transactions. + T5: s_setprio(1) around the MFMA clusters — flash's
// independent blocks sit at different k-phases per CU (the m191 regime where
// setprio pays; null in barrier-lockstep GEMMs).
// QBLK=64, shift-free softmax, double-buffered K/V, Q read from LDS each
// tile. P stored TRUNCATED (bits>>16); row-sum on the MFMA pipe via all-ones
// B operand reading the SAME truncated bf16 P as PV. q pre-scaled by
// 0.125*log2e -> e = exp2(s).
// ---------------------------------------------------------------------------
__device__ __forceinline__ void flash_stage_kv(
    const u16* __restrict__ kb, const u16* __restrict__ vT,
    int b, int kt, u16* __restrict__ Ksb, u16* __restrict__ Vsb,
    const int* row_c, const int* off_c, int c0)
{
    const size_t kt0 = (size_t)(b * TSEQ + kt * 64);
    #pragma unroll
    for (int hf = 0; hf < 2; ++hf) {
        int cc = c0 + hf * 256;
        async_copy16(kb + (kt0 + row_c[hf]) * HDIM + off_c[hf], Ksb + cc * 8);
        async_copy16(vT + (size_t)(b * HDIM + row_c[hf]) * TSEQ + kt * 64 + off_c[hf],
                     Vsb + cc * 8);
    }
}

__device__ __forceinline__ void flash_tile(
    const u16* __restrict__ Ksb, const u16* __restrict__ Vsb,
    const u16* __restrict__ Qs, u16* __restrict__ Pw,
    int wave, int ln16, int quad, bool diag,
    f32x4* lacc, f32x4* oacc)
{
    // ---- S = Q.K^T ----
    f32x4 sv[4];
    #pragma unroll
    for (int t = 0; t < 4; ++t) sv[t] = (f32x4){0.f, 0.f, 0.f, 0.f};
    __builtin_amdgcn_s_setprio(1);
    #pragma unroll
    for (int kk2 = 0; kk2 < 2; ++kk2) {
        short8 af = *(const short8*)&Qs[(wave * 128 + kk2 * 64 + quad * 16 + ln16) * 8];
        #pragma unroll
        for (int t = 0; t < 4; ++t) {
            short8 bf = *(const short8*)&Ksb[(t * 128 + kk2 * 64 + quad * 16 + ln16) * 8];
            sv[t] = __builtin_amdgcn_mfma_f32_16x16x32_bf16(af, bf, sv[t], 0, 0, 0);
        }
    }
    __builtin_amdgcn_s_setprio(0);

    // ---- e = exp2(s') (0 if masked); truncated bf16 into Pw ----
    if (diag) {
        #pragma unroll
        for (int t = 0; t < 4; ++t) {
            int key = t * 16 + ln16;
            #pragma unroll
            for (int r = 0; r < 4; ++r) {
                float e = (key > wave * 16 + quad * 4 + r) ? 0.f : exp2f(sv[t][r]);
                Pw[(quad * 4 + r) * 72 + t * 16 + ln16] =
                    (u16)(__float_as_uint(e) >> 16);
            }
        }
    } else {
        #pragma unroll
        for (int t = 0; t < 4; ++t)
            #pragma unroll
            for (int r = 0; r < 4; ++r) {
                float e = exp2f(sv[t][r]);
                Pw[(quad * 4 + r) * 72 + t * 16 + ln16] =
                    (u16)(__float_as_uint(e) >> 16);
            }
    }

    // ---- O += P.V ; denominator via ones-column MFMA on same P ----
    const short8 ones = {0x3F80, 0x3F80, 0x3F80, 0x3F80,
                         0x3F80, 0x3F80, 0x3F80, 0x3F80};   // bf16 1.0
    __builtin_amdgcn_s_setprio(1);
    #pragma unroll
    for (int kk2 = 0; kk2 < 2; ++kk2) {
        short8 pf = *(const short8*)&Pw[ln16 * 72 + kk2 * 32 + quad * 8];
        *lacc = __builtin_amdgcn_mfma_f32_16x16x32_bf16(pf, ones, *lacc, 0, 0, 0);
        #pragma unroll
        for (int t = 0; t < 4; ++t) {
            short8 vf = *(const short8*)&Vsb[(t * 128 + kk2 * 64 + quad * 16 + ln16) * 8];
            oacc[t] = __builtin_amdgcn_mfma_f32_16x16x32_bf16(pf, vf, oacc[t], 0, 0, 0);
        }
    }
    __builtin_amdgcn_s_setprio(0);
}

__global__ __launch_bounds__(256) void flash_mfma_kernel(
    const u16* __restrict__ qb, const u16* __restrict__ kb,
    const u16* __restrict__ vT, u16* __restrict__ o)
{
    const int id  = blockIdx.x;
    const int qt  = 31 - (id >> 5);   // longest blocks first (LPT)
    const int hb  = id & 31;
    const int h   = hb >> 1;
    const int b   = hb & 1;
    __shared__ __align__(16) u16 Qs [512 * 8];       // 8 KB
    __shared__ __align__(16) u16 Ks0[512 * 8];       // 8 KB  (double buffer)
    __shared__ __align__(16) u16 Ks1[512 * 8];       // 8 KB
    __shared__ __align__(16) u16 Vs0[512 * 8];       // 8 KB
    __shared__ __align__(16) u16 Vs1[512 * 8];       // 8 KB
    __shared__ __align__(16) u16 Ps[4 * 16 * 72];    // 9 KB, per-wave [16][72]

    const int tid  = threadIdx.x;
    const int wave = tid >> 6, lane = tid & 63;
    const int ln16 = lane & 15, quad = lane >> 4;

    const int c0 = tid;
    int row_c[2], off_c[2];
    #pragma unroll
    for (int hf = 0; hf < 2; ++hf) {
        int c = c0 + hf * 256;
        row_c[hf] = ((c >> 7) << 4) | (c & 15);
        off_c[hf] = ((c >> 6) & 1) * 32 + ((c >> 4) & 3) * 8;
    }

    u16* Pw = &Ps[wave * 16 * 72];

    // ---- stage Q + K/V tile 0 ----
    #pragma unroll
    for (int hf = 0; hf < 2; ++hf)
        async_copy16(
            qb + (size_t)(b * TSEQ + qt * 64 + row_c[hf]) * CDIM + h * HDIM + off_c[hf],
            Qs + (c0 + hf * 256) * 8);
    flash_stage_kv(kb, vT, b, 0, Ks0, Vs0, row_c, off_c, c0);

    f32x4 lacc = (f32x4){0.f, 0.f, 0.f, 0.f};
    f32x4 oacc[4];
    #pragma unroll
    for (int t = 0; t < 4; ++t) oacc[t] = (f32x4){0.f, 0.f, 0.f, 0.f};

    int kt = 0;
    while (true) {
        __syncthreads();    // buf0 for kt ready; all waves done reading buf1
        if (kt < qt) flash_stage_kv(kb, vT, b, kt + 1, Ks1, Vs1, row_c, off_c, c0);
        flash_tile(Ks0, Vs0, Qs, Pw, wave, ln16, quad, kt == qt, &lacc, oacc);
        if (++kt > qt) break;
        __syncthreads();    // buf1 for kt ready; all waves done reading buf0
        if (kt < qt) flash_stage_kv(kb, vT, b, kt + 1, Ks0, Vs0, row_c, off_c, c0);
        flash_tile(Ks1, Vs1, Qs, Pw, wave, ln16, quad, kt == qt, &lacc, oacc);
        if (++kt > qt) break;
    }

    // ---- epilogue: denominators already fully reduced in lacc ----
    float inv[4];
    #pragma unroll
    for (int r = 0; r < 4; ++r) inv[r] = 1.0f / lacc[r];
    #pragma unroll
    for (int t = 0; t < 4; ++t) {
        #pragma unroll
        for (int r = 0; r < 4; ++r) {
            int row = qt * 64 + wave * 16 + quad * 4 + r;
            int d   = t * 16 + ln16;
            o[(size_t)(b * TSEQ + row) * CDIM + h * HDIM + d] = f2b(oacc[t][r] * inv[r]);
        }
    }
}

// ---------------------------------------------------------------------------
extern "C" void kernel_launch(void* const* d_in, const int* in_sizes, int n_in,
                              void* d_out, int out_size, void* d_ws, size_t ws_size,
                              hipStream_t stream)
{
    const float* x  = (const float*)d_in[0];
    const float* Wq = (const float*)d_in[1];
    const float* bq = (const float*)d_in[2];
    const float* Wk = (const float*)d_in[3];
    const float* bk = (const float*)d_in[4];
    const float* Wv = (const float*)d_in[5];
    const float* bv = (const float*)d_in[6];
    const float* Wo = (const float*)d_in[7];
    const float* bo = (const float*)d_in[8];
    float* out = (float*)d_out;

    const size_t MB = 1u << 20;
    char* w = (char*)d_ws;
    u16*   xb   = (u16*)(w);                   //  8 MB [BT][1024] bf16
    u16*   aob  = (u16*)(w);                   //  alias: xb dead after qkv GEMM
    u16*   qb   = (u16*)(w + 8 * MB);          //  8 MB [BT][1024] rope'd, scaled
    u16*   kb   = (u16*)(w + 16 * MB);         //  0.5 MB [BT][64]
    u16*   vT   = (u16*)(w + 16 * MB + 512 * 1024);   // 0.5 MB [B][64][T]
    u16*   Wqkvt= (u16*)(w + 17 * MB);         //  2.25 MB [1152][1024]
    u16*   Wot  = (u16*)(w + 20 * MB);         //  2 MB
    float* bqkv = (float*)(w + 22 * MB);       //  4.5 KB

    // 1) x-cast + weight transposes + bias concat, one launch
    prep_kernel<<<dim3(4641), dim3(256), 0, stream>>>(
        x, Wq, Wk, Wv, Wo, bq, bk, bv, xb, Wqkvt, Wot, bqkv);
    // 2) fused qkv projection + rope + v-transpose -> qb, kb, vT (bf16)
    gemm_qkv_kernel<<<dim3(NQKV / 128, BT / 128), dim3(256), 0, stream>>>(
        xb, Wqkvt, bqkv, qb, kb, vT);
    // 3) flash attention -> aob (overwrites dead xb)
    flash_mfma_kernel<<<dim3(32 * NHEAD * BSZ), dim3(256), 0, stream>>>(
        qb, kb, vT, aob);
    // 4) output projection
    gemm_mfma_kernel<<<dim3(CDIM / 128, BT / 128), dim3(256), 0, stream>>>(
        aob, Wot, bo, out, BT, CDIM, CDIM);
}

// Round 10
// 190.096 us; speedup vs baseline: 1.2741x; 1.0079x over previous
//
#include <hip/hip_runtime.h>
#include <math.h>

#define BSZ   2
#define TSEQ  2048
#define CDIM  1024
#define NHEAD 16
#define HDIM  64
#define BT    (BSZ*TSEQ)
#define NQKV  1152   // 1024 q + 64 k + 64 v

typedef __attribute__((ext_vector_type(8))) short short8;
typedef __attribute__((ext_vector_type(4))) float f32x4;
typedef unsigned short u16;
typedef unsigned int   u32;

__device__ __forceinline__ u16 f2b(float f) {
    union { float f; u32 u; } c; c.f = f;
    u32 u = c.u;
    u += 0x7fffu + ((u >> 16) & 1u);   // round-nearest-even
    return (u16)(u >> 16);
}
__device__ __forceinline__ u32 pack2(float lo, float hi) {
    return (u32)f2b(lo) | ((u32)f2b(hi) << 16);
}

// async global->LDS, 16B per lane. LDS dest must be wave-uniform base + lane*16.
__device__ __forceinline__ void async_copy16(const void* g, void* l) {
    __builtin_amdgcn_global_load_lds(
        (__attribute__((address_space(1))) const void*)g,
        (__attribute__((address_space(3))) void*)l,
        16, 0, 0);
}

// ---------------------------------------------------------------------------
// one 64x64 transpose+cast tile: W[K][Nw] fp32 -> Wt[nofs+n][K] bf16
// ---------------------------------------------------------------------------
__device__ __forceinline__ void transpose_tile(
    const float* __restrict__ W, u16* __restrict__ Wt,
    int K, int Nw, int nofs, int bx, int by, float (*T)[65])
{
    const int tid = threadIdx.x;
    const int k0 = by * 64, n0 = bx * 64;
    #pragma unroll
    for (int i = 0; i < 16; ++i) {
        int idx = i * 256 + tid, r = idx >> 6, c = idx & 63;
        T[r][c] = W[(size_t)(k0 + r) * Nw + n0 + c];
    }
    __syncthreads();
    #pragma unroll
    for (int i = 0; i < 16; ++i) {
        int idx = i * 256 + tid, rn = idx >> 6, ck = idx & 63;
        Wt[(size_t)(nofs + n0 + rn) * K + k0 + ck] = f2b(T[ck][rn]);
    }
}

// x-cast + all weight transposes + bias concat in ONE launch (blockIdx switch)
__global__ __launch_bounds__(256) void prep_kernel(
    const float* __restrict__ x,
    const float* __restrict__ Wq, const float* __restrict__ Wk,
    const float* __restrict__ Wv, const float* __restrict__ Wo,
    const float* __restrict__ bq, const float* __restrict__ bk,
    const float* __restrict__ bv,
    u16* __restrict__ xb,
    u16* __restrict__ Wqkvt, u16* __restrict__ Wot, float* __restrict__ bqkv)
{
    __shared__ float T[64][65];
    const int bid = blockIdx.x;
    if (bid < 4096) {
        // x -> bf16, 4 elems/thread (4096 blocks x 1024 elems)
        int i = bid * 256 + threadIdx.x;
        float4 f = ((const float4*)x)[i];
        u16* d = xb + (size_t)i * 4;
        d[0] = f2b(f.x); d[1] = f2b(f.y); d[2] = f2b(f.z); d[3] = f2b(f.w);
    } else if (bid < 4352) {
        int b2 = bid - 4096;
        transpose_tile(Wq, Wqkvt, 1024, 1024, 0, b2 & 15, b2 >> 4, T);
    } else if (bid < 4368) {
        transpose_tile(Wk, Wqkvt, 1024, 64, 1024, 0, bid - 4352, T);
    } else if (bid < 4384) {
        transpose_tile(Wv, Wqkvt, 1024, 64, 1088, 0, bid - 4368, T);
    } else if (bid < 4640) {
        int b2 = bid - 4384;
        transpose_tile(Wo, Wot, 1024, 1024, 0, b2 & 15, b2 >> 4, T);
    } else {
        for (int i = threadIdx.x; i < NQKV; i += 256)
            bqkv[i] = (i < 1024) ? bq[i] : (i < 1088 ? bk[i - 1024] : bv[i - 1088]);
    }
}

// ---------------------------------------------------------------------------
// 128x128 GEMM inner step: 8 ds_read_b128 + 16 MFMA (wave owns 64x64 = 4x4)
// ---------------------------------------------------------------------------
__device__ __forceinline__ void gemm_step128(
    const u16* __restrict__ As, const u16* __restrict__ Bs,
    int wm, int wn, int quad, int ln16, f32x4 (*acc)[4])
{
    short8 af[4], bf[4];
    #pragma unroll
    for (int mt = 0; mt < 4; ++mt)
        af[mt] = *(const short8*)&As[(((wm * 4 + mt) * 64) + quad * 16 + ln16) * 8];
    #pragma unroll
    for (int nt = 0; nt < 4; ++nt)
        bf[nt] = *(const short8*)&Bs[(((wn * 4 + nt) * 64) + quad * 16 + ln16) * 8];
    #pragma unroll
    for (int mt = 0; mt < 4; ++mt)
        #pragma unroll
        for (int nt = 0; nt < 4; ++nt)
            acc[mt][nt] = __builtin_amdgcn_mfma_f32_16x16x32_bf16(
                af[mt], bf[nt], acc[mt][nt], 0, 0, 0);
}

__device__ __forceinline__ void gemm_stage4(
    const u16* ag0, const u16* ag1, const u16* bg0, const u16* bg1,
    u16* al0, u16* al1, u16* bl0, u16* bl1)
{
    async_copy16(ag0, al0);
    async_copy16(ag1, al1);
    async_copy16(bg0, bl0);
    async_copy16(bg1, bl1);
}

// Counted-vmcnt 3-buffer 128x128 K-loop (T3/T4): 4 staging loads per tile,
// 2 tiles staged ahead (8 in flight); wait vmcnt(4) retires exactly the
// oldest tile's 4 loads before the barrier -> after the barrier tile k is
// collectively resident while the next tile's loads stay in flight. vmcnt
// reaches 0 only on the final iteration. K=1024, BK=32 -> 32 tiles = 3x10+2.
#define STAGE128(KOFS, I)                                                     \
    gemm_stage4(ag0 + (KOFS), ag1 + (KOFS), bg0 + (KOFS), bg1 + (KOFS),       \
                aLo##I, aHi##I, bLo##I, bHi##I)

#define GEMM128_PIPE_LOOP()                                                   \
    STAGE128(0, 0);                                                           \
    STAGE128(32, 1);                                                          \
    for (int k = 0; k < 30; k += 3) {                                         \
        const int kb = k * 32;                                                \
        asm volatile("s_waitcnt vmcnt(4)" ::: "memory");                      \
        __builtin_amdgcn_s_barrier();                                         \
        STAGE128(kb + 64, 2);                                                 \
        gemm_step128(AsC[0], BsC[0], wm, wn, quad, ln16, acc);                \
        asm volatile("s_waitcnt vmcnt(4)" ::: "memory");                      \
        __builtin_amdgcn_s_barrier();                                         \
        STAGE128(kb + 96, 0);                                                 \
        gemm_step128(AsC[1], BsC[1], wm, wn, quad, ln16, acc);                \
        asm volatile("s_waitcnt vmcnt(4)" ::: "memory");                      \
        __builtin_amdgcn_s_barrier();                                         \
        STAGE128(kb + 128, 1);                                                \
        gemm_step128(AsC[2], BsC[2], wm, wn, quad, ln16, acc);                \
    }                                                                         \
    asm volatile("s_waitcnt vmcnt(4)" ::: "memory");                          \
    __builtin_amdgcn_s_barrier();                                             \
    gemm_step128(AsC[0], BsC[0], wm, wn, quad, ln16, acc);                    \
    asm volatile("s_waitcnt vmcnt(0)" ::: "memory");                          \
    __builtin_amdgcn_s_barrier();                                             \
    gemm_step128(AsC[1], BsC[1], wm, wn, quad, ln16, acc);

#define GEMM128_SETUP(Aptr, Btptr, Kdim)                                      \
    const int tid  = threadIdx.x;                                             \
    const int wave = tid >> 6, lane = tid & 63;                               \
    const int ln16 = lane & 15, quad = lane >> 4;                             \
    const int wm = wave >> 1, wn = wave & 1;                                  \
    const int m0 = blockIdx.y * 128, n0 = blockIdx.x * 128;                   \
    const int c_row = (wave << 4) + ln16;                                     \
    const int c_k   = quad * 8;                                               \
    const u16* ag0 = &(Aptr) [(size_t)(m0 + c_row)       * (Kdim) + c_k];     \
    const u16* ag1 = &(Aptr) [(size_t)(m0 + 64 + c_row)  * (Kdim) + c_k];     \
    const u16* bg0 = &(Btptr)[(size_t)(n0 + c_row)       * (Kdim) + c_k];     \
    const u16* bg1 = &(Btptr)[(size_t)(n0 + 64 + c_row)  * (Kdim) + c_k];     \
    u16* aLo0 = &AsC[0][(size_t)wave * 512];                                  \
    u16* aLo1 = &AsC[1][(size_t)wave * 512];                                  \
    u16* aLo2 = &AsC[2][(size_t)wave * 512];                                  \
    u16* aHi0 = &AsC[0][(size_t)(wave + 4) * 512];                            \
    u16* aHi1 = &AsC[1][(size_t)(wave + 4) * 512];                            \
    u16* aHi2 = &AsC[2][(size_t)(wave + 4) * 512];                            \
    u16* bLo0 = &BsC[0][(size_t)wave * 512];                                  \
    u16* bLo1 = &BsC[1][(size_t)wave * 512];                                  \
    u16* bLo2 = &BsC[2][(size_t)wave * 512];                                  \
    u16* bHi0 = &BsC[0][(size_t)(wave + 4) * 512];                            \
    u16* bHi1 = &BsC[1][(size_t)(wave + 4) * 512];                            \
    u16* bHi2 = &BsC[2][(size_t)(wave + 4) * 512];                            \
    f32x4 acc[4][4];                                                          \
    _Pragma("unroll")                                                         \
    for (int i = 0; i < 4; ++i)                                               \
        _Pragma("unroll")                                                     \
        for (int j = 0; j < 4; ++j) acc[i][j] = (f32x4){0.f, 0.f, 0.f, 0.f};

// ---------------------------------------------------------------------------
// Fused qkv projection: 128x128 tile, BK=32, 4 waves (2x2, 64x64 each),
// counted-vmcnt 3-buffer pipeline. Epilogue (R1-verified): RoPE q (pre-scaled
// 0.125*log2e so flash uses exp2), RoPE k, transpose v.
// ---------------------------------------------------------------------------
__global__ __launch_bounds__(256) void gemm_qkv_kernel(
    const u16* __restrict__ A, const u16* __restrict__ Bt,
    const float* __restrict__ bias,
    u16* __restrict__ qb, u16* __restrict__ kb, u16* __restrict__ vT)
{
    __shared__ __align__(16) u16 AsC[3][128 * 32];   // 24 KB
    __shared__ __align__(16) u16 BsC[3][128 * 32];   // 24 KB
    GEMM128_SETUP(A, Bt, CDIM);

    GEMM128_PIPE_LOOP();

    // ---- bias ----
    #pragma unroll
    for (int mt = 0; mt < 4; ++mt)
        #pragma unroll
        for (int nt = 0; nt < 4; ++nt) {
            float bb = bias[n0 + wn * 64 + nt * 16 + ln16];
            #pragma unroll
            for (int r = 0; r < 4; ++r) acc[mt][nt][r] += bb;
        }

    const int col0 = n0 + wn * 64;   // head-aligned category base
    if (col0 < 1024) {
        // ---- q: rope + (1/8)*log2e scale (flash uses exp2) -> qb ----
        const int hh = col0 >> 6;
        #pragma unroll
        for (int nt = 0; nt < 2; ++nt) {
            int j = nt * 16 + ln16;
            float fr = exp2f(-0.41524101186092029f * (float)j);  // 10000^(-j/32)
            #pragma unroll
            for (int mt = 0; mt < 4; ++mt)
                #pragma unroll
                for (int r = 0; r < 4; ++r) {
                    int m = m0 + wm * 64 + mt * 16 + quad * 4 + r;
                    float sn, cs;
                    __sincosf((float)(m & (TSEQ - 1)) * fr, &sn, &cs);
                    float t1 = acc[mt][nt][r], t2 = acc[mt][nt + 2][r];
                    u16* o = qb + (size_t)m * CDIM + hh * 64 + j;
                    o[0]  = f2b(fmaf(t1, cs,  t2 * sn) * 0.18033688011112043f);
                    o[32] = f2b(fmaf(t1, sn, -t2 * cs) * 0.18033688011112043f);
                }
        }
    } else if (wn == 0) {
        // ---- k: rope -> kb[bt][64] ----
        #pragma unroll
        for (int nt = 0; nt < 2; ++nt) {
            int j = nt * 16 + ln16;
            float fr = exp2f(-0.41524101186092029f * (float)j);
            #pragma unroll
            for (int mt = 0; mt < 4; ++mt)
                #pragma unroll
                for (int r = 0; r < 4; ++r) {
                    int m = m0 + wm * 64 + mt * 16 + quad * 4 + r;
                    float sn, cs;
                    __sincosf((float)(m & (TSEQ - 1)) * fr, &sn, &cs);
                    float t1 = acc[mt][nt][r], t2 = acc[mt][nt + 2][r];
                    u16* o = kb + (size_t)m * HDIM + j;
                    o[0]  = f2b(fmaf(t1, cs,  t2 * sn));
                    o[32] = f2b(fmaf(t1, sn, -t2 * cs));
                }
        }
    } else {
        // ---- v: transpose -> vT[b][d][T] (4 consecutive rows = 8B store) ----
        #pragma unroll
        for (int nt = 0; nt < 4; ++nt) {
            int d = nt * 16 + ln16;
            #pragma unroll
            for (int mt = 0; mt < 4; ++mt) {
                int mr = m0 + wm * 64 + mt * 16 + quad * 4;
                int b  = mr >> 11, tq = mr & (TSEQ - 1);
                uint2 val;
                val.x = pack2(acc[mt][nt][0], acc[mt][nt][1]);
                val.y = pack2(acc[mt][nt][2], acc[mt][nt][3]);
                *(uint2*)&vT[(size_t)(b * HDIM + d) * TSEQ + tq] = val;
            }
        }
    }
}

// ---------------------------------------------------------------------------
// Output projection: Y fp32 = A(bf16) @ Bt(bf16)^T + bias. 128x128 tile,
// BK=32, 4 waves (2x2), counted-vmcnt 3-buffer pipeline.
// ---------------------------------------------------------------------------
__global__ __launch_bounds__(256) void gemm_mfma_kernel(
    const u16* __restrict__ A, const u16* __restrict__ Bt,
    const float* __restrict__ bias, float* __restrict__ Y,
    int M, int N, int K)
{
    __shared__ __align__(16) u16 AsC[3][128 * 32];   // 24 KB
    __shared__ __align__(16) u16 BsC[3][128 * 32];   // 24 KB
    GEMM128_SETUP(A, Bt, K);

    GEMM128_PIPE_LOOP();

    #pragma unroll
    for (int mt = 0; mt < 4; ++mt)
        #pragma unroll
        for (int nt = 0; nt < 4; ++nt) {
            int n = n0 + wn * 64 + nt * 16 + ln16;
            float bb = bias[n];
            #pragma unroll
            for (int r = 0; r < 4; ++r) {
                int m = m0 + wm * 64 + mt * 16 + quad * 4 + r;
                Y[(size_t)m * N + n] = acc[mt][nt][r] + bb;
            }
        }
}

// ---------------------------------------------------------------------------
// Flash attention (R4 measured-best inner structure; setprio removed — R9
// measured it null-to-negative, consistent with m190).
// NEW: load-balanced block->work mapping. Under modular dispatch, blocks
// c, c+256, c+512, c+768 colocate on one CU (256 = 0 mod 8 XCDs, and
// CU-slot stride 32 | 256/8). Old LPT map gave those rounds qts
// {31-g, 23-g, 15-g, 7-g} -> per-CU iter sums 80-4g: CUs 0-31 carried 80,
// CUs 224-255 only 52 (54% spread -> measured 22% occupancy). New map
// assigns rounds {31-g, 16+g, 15-g, g}: every CU sums to exactly 66 iters,
// longest blocks still first, smallest (1-8 iters) fill the tail.
// Pure permutation: correctness unaffected.
// QBLK=64, shift-free softmax, double-buffered K/V, Q read from LDS each
// tile. P stored TRUNCATED (bits>>16); row-sum on the MFMA pipe via all-ones
// B operand reading the SAME truncated bf16 P as PV. q pre-scaled by
// 0.125*log2e -> e = exp2(s).
// ---------------------------------------------------------------------------
__device__ __forceinline__ void flash_stage_kv(
    const u16* __restrict__ kb, const u16* __restrict__ vT,
    int b, int kt, u16* __restrict__ Ksb, u16* __restrict__ Vsb,
    const int* row_c, const int* off_c, int c0)
{
    const size_t kt0 = (size_t)(b * TSEQ + kt * 64);
    #pragma unroll
    for (int hf = 0; hf < 2; ++hf) {
        int cc = c0 + hf * 256;
        async_copy16(kb + (kt0 + row_c[hf]) * HDIM + off_c[hf], Ksb + cc * 8);
        async_copy16(vT + (size_t)(b * HDIM + row_c[hf]) * TSEQ + kt * 64 + off_c[hf],
                     Vsb + cc * 8);
    }
}

__device__ __forceinline__ void flash_tile(
    const u16* __restrict__ Ksb, const u16* __restrict__ Vsb,
    const u16* __restrict__ Qs, u16* __restrict__ Pw,
    int wave, int ln16, int quad, bool diag,
    f32x4* lacc, f32x4* oacc)
{
    // ---- S = Q.K^T ----
    f32x4 sv[4];
    #pragma unroll
    for (int t = 0; t < 4; ++t) sv[t] = (f32x4){0.f, 0.f, 0.f, 0.f};
    #pragma unroll
    for (int kk2 = 0; kk2 < 2; ++kk2) {
        short8 af = *(const short8*)&Qs[(wave * 128 + kk2 * 64 + quad * 16 + ln16) * 8];
        #pragma unroll
        for (int t = 0; t < 4; ++t) {
            short8 bf = *(const short8*)&Ksb[(t * 128 + kk2 * 64 + quad * 16 + ln16) * 8];
            sv[t] = __builtin_amdgcn_mfma_f32_16x16x32_bf16(af, bf, sv[t], 0, 0, 0);
        }
    }

    // ---- e = exp2(s') (0 if masked); truncated bf16 into Pw ----
    if (diag) {
        #pragma unroll
        for (int t = 0; t < 4; ++t) {
            int key = t * 16 + ln16;
            #pragma unroll
            for (int r = 0; r < 4; ++r) {
                float e = (key > wave * 16 + quad * 4 + r) ? 0.f : exp2f(sv[t][r]);
                Pw[(quad * 4 + r) * 72 + t * 16 + ln16] =
                    (u16)(__float_as_uint(e) >> 16);
            }
        }
    } else {
        #pragma unroll
        for (int t = 0; t < 4; ++t)
            #pragma unroll
            for (int r = 0; r < 4; ++r) {
                float e = exp2f(sv[t][r]);
                Pw[(quad * 4 + r) * 72 + t * 16 + ln16] =
                    (u16)(__float_as_uint(e) >> 16);
            }
    }

    // ---- O += P.V ; denominator via ones-column MFMA on same P ----
    const short8 ones = {0x3F80, 0x3F80, 0x3F80, 0x3F80,
                         0x3F80, 0x3F80, 0x3F80, 0x3F80};   // bf16 1.0
    #pragma unroll
    for (int kk2 = 0; kk2 < 2; ++kk2) {
        short8 pf = *(const short8*)&Pw[ln16 * 72 + kk2 * 32 + quad * 8];
        *lacc = __builtin_amdgcn_mfma_f32_16x16x32_bf16(pf, ones, *lacc, 0, 0, 0);
        #pragma unroll
        for (int t = 0; t < 4; ++t) {
            short8 vf = *(const short8*)&Vsb[(t * 128 + kk2 * 64 + quad * 16 + ln16) * 8];
            oacc[t] = __builtin_amdgcn_mfma_f32_16x16x32_bf16(pf, vf, oacc[t], 0, 0, 0);
        }
    }
}

__global__ __launch_bounds__(256) void flash_mfma_kernel(
    const u16* __restrict__ qb, const u16* __restrict__ kb,
    const u16* __restrict__ vT, u16* __restrict__ o)
{
    const int id  = blockIdx.x;
    const int rr  = id >> 8;          // colocation round (blocks c,c+256,... share a CU)
    const int c   = id & 255;
    const int g   = c >> 5;           // 0..7
    const int hb  = c & 31;
    // balanced map: per-CU iter sum = (32-g)+(17+g)+(16-g)+(1+g) = 66 for all g
    const int qt  = (rr == 0) ? 31 - g : (rr == 1) ? 16 + g : (rr == 2) ? 15 - g : g;
    const int h   = hb >> 1;
    const int b   = hb & 1;
    __shared__ __align__(16) u16 Qs [512 * 8];       // 8 KB
    __shared__ __align__(16) u16 Ks0[512 * 8];       // 8 KB  (double buffer)
    __shared__ __align__(16) u16 Ks1[512 * 8];       // 8 KB
    __shared__ __align__(16) u16 Vs0[512 * 8];       // 8 KB
    __shared__ __align__(16) u16 Vs1[512 * 8];       // 8 KB
    __shared__ __align__(16) u16 Ps[4 * 16 * 72];    // 9 KB, per-wave [16][72]

    const int tid  = threadIdx.x;
    const int wave = tid >> 6, lane = tid & 63;
    const int ln16 = lane & 15, quad = lane >> 4;

    const int c0 = tid;
    int row_c[2], off_c[2];
    #pragma unroll
    for (int hf = 0; hf < 2; ++hf) {
        int cc = c0 + hf * 256;
        row_c[hf] = ((cc >> 7) << 4) | (cc & 15);
        off_c[hf] = ((cc >> 6) & 1) * 32 + ((cc >> 4) & 3) * 8;
    }

    u16* Pw = &Ps[wave * 16 * 72];

    // ---- stage Q + K/V tile 0 ----
    #pragma unroll
    for (int hf = 0; hf < 2; ++hf)
        async_copy16(
            qb + (size_t)(b * TSEQ + qt * 64 + row_c[hf]) * CDIM + h * HDIM + off_c[hf],
            Qs + (c0 + hf * 256) * 8);
    flash_stage_kv(kb, vT, b, 0, Ks0, Vs0, row_c, off_c, c0);

    f32x4 lacc = (f32x4){0.f, 0.f, 0.f, 0.f};
    f32x4 oacc[4];
    #pragma unroll
    for (int t = 0; t < 4; ++t) oacc[t] = (f32x4){0.f, 0.f, 0.f, 0.f};

    int kt = 0;
    while (true) {
        __syncthreads();    // buf0 for kt ready; all waves done reading buf1
        if (kt < qt) flash_stage_kv(kb, vT, b, kt + 1, Ks1, Vs1, row_c, off_c, c0);
        flash_tile(Ks0, Vs0, Qs, Pw, wave, ln16, quad, kt == qt, &lacc, oacc);
        if (++kt > qt) break;
        __syncthreads();    // buf1 for kt ready; all waves done reading buf0
        if (kt < qt) flash_stage_kv(kb, vT, b, kt + 1, Ks0, Vs0, row_c, off_c, c0);
        flash_tile(Ks1, Vs1, Qs, Pw, wave, ln16, quad, kt == qt, &lacc, oacc);
        if (++kt > qt) break;
    }

    // ---- epilogue: denominators already fully reduced in lacc ----
    float inv[4];
    #pragma unroll
    for (int r = 0; r < 4; ++r) inv[r] = 1.0f / lacc[r];
    #pragma unroll
    for (int t = 0; t < 4; ++t) {
        #pragma unroll
        for (int r = 0; r < 4; ++r) {
            int row = qt * 64 + wave * 16 + quad * 4 + r;
            int d   = t * 16 + ln16;
            o[(size_t)(b * TSEQ + row) * CDIM + h * HDIM + d] = f2b(oacc[t][r] * inv[r]);
        }
    }
}

// ---------------------------------------------------------------------------
extern "C" void kernel_launch(void* const* d_in, const int* in_sizes, int n_in,
                              void* d_out, int out_size, void* d_ws, size_t ws_size,
                              hipStream_t stream)
{
    const float* x  = (const float*)d_in[0];
    const float* Wq = (const float*)d_in[1];
    const float* bq = (const float*)d_in[2];
    const float* Wk = (const float*)d_in[3];
    const float* bk = (const float*)d_in[4];
    const float* Wv = (const float*)d_in[5];
    const float* bv = (const float*)d_in[6];
    const float* Wo = (const float*)d_in[7];
    const float* bo = (const float*)d_in[8];
    float* out = (float*)d_out;

    const size_t MB = 1u << 20;
    char* w = (char*)d_ws;
    u16*   xb   = (u16*)(w);                   //  8 MB [BT][1024] bf16
    u16*   aob  = (u16*)(w);                   //  alias: xb dead after qkv GEMM
    u16*   qb   = (u16*)(w + 8 * MB);          //  8 MB [BT][1024] rope'd, scaled
    u16*   kb   = (u16*)(w + 16 * MB);         //  0.5 MB [BT][64]
    u16*   vT   = (u16*)(w + 16 * MB + 512 * 1024);   // 0.5 MB [B][64][T]
    u16*   Wqkvt= (u16*)(w + 17 * MB);         //  2.25 MB [1152][1024]
    u16*   Wot  = (u16*)(w + 20 * MB);         //  2 MB
    float* bqkv = (float*)(w + 22 * MB);       //  4.5 KB

    // 1) x-cast + weight transposes + bias concat, one launch
    prep_kernel<<<dim3(4641), dim3(256), 0, stream>>>(
        x, Wq, Wk, Wv, Wo, bq, bk, bv, xb, Wqkvt, Wot, bqkv);
    // 2) fused qkv projection + rope + v-transpose -> qb, kb, vT (bf16)
    gemm_qkv_kernel<<<dim3(NQKV / 128, BT / 128), dim3(256), 0, stream>>>(
        xb, Wqkvt, bqkv, qb, kb, vT);
    // 3) flash attention -> aob (overwrites dead xb)
    flash_mfma_kernel<<<dim3(32 * NHEAD * BSZ), dim3(256), 0, stream>>>(
        qb, kb, vT, aob);
    // 4) output projection
    gemm_mfma_kernel<<<dim3(CDIM / 128, BT / 128), dim3(256), 0, stream>>>(
        aob, Wot, bo, out, BT, CDIM, CDIM);
}

// Round 11
// 188.386 us; speedup vs baseline: 1.2857x; 1.0091x over previous
//
#include <hip/hip_runtime.h>
#include <math.h>

#define BSZ   2
#define TSEQ  2048
#define CDIM  1024
#define NHEAD 16
#define HDIM  64
#define BT    (BSZ*TSEQ)
#define NQKV  1152   // 1024 q + 64 k + 64 v

typedef __attribute__((ext_vector_type(8))) short short8;
typedef __attribute__((ext_vector_type(4))) float f32x4;
typedef unsigned short u16;
typedef unsigned int   u32;

__device__ __forceinline__ u16 f2b(float f) {
    union { float f; u32 u; } c; c.f = f;
    u32 u = c.u;
    u += 0x7fffu + ((u >> 16) & 1u);   // round-nearest-even
    return (u16)(u >> 16);
}
__device__ __forceinline__ u32 pack2(float lo, float hi) {
    return (u32)f2b(lo) | ((u32)f2b(hi) << 16);
}

// async global->LDS, 16B per lane. LDS dest must be wave-uniform base + lane*16.
__device__ __forceinline__ void async_copy16(const void* g, void* l) {
    __builtin_amdgcn_global_load_lds(
        (__attribute__((address_space(1))) const void*)g,
        (__attribute__((address_space(3))) void*)l,
        16, 0, 0);
}

// ---------------------------------------------------------------------------
// one 64x64 transpose+cast tile: W[K][Nw] fp32 -> Wt[nofs+n][K] bf16
// ---------------------------------------------------------------------------
__device__ __forceinline__ void transpose_tile(
    const float* __restrict__ W, u16* __restrict__ Wt,
    int K, int Nw, int nofs, int bx, int by, float (*T)[65])
{
    const int tid = threadIdx.x;
    const int k0 = by * 64, n0 = bx * 64;
    #pragma unroll
    for (int i = 0; i < 16; ++i) {
        int idx = i * 256 + tid, r = idx >> 6, c = idx & 63;
        T[r][c] = W[(size_t)(k0 + r) * Nw + n0 + c];
    }
    __syncthreads();
    #pragma unroll
    for (int i = 0; i < 16; ++i) {
        int idx = i * 256 + tid, rn = idx >> 6, ck = idx & 63;
        Wt[(size_t)(nofs + n0 + rn) * K + k0 + ck] = f2b(T[ck][rn]);
    }
}

// x-cast + all weight transposes + bias concat in ONE launch (blockIdx switch)
__global__ __launch_bounds__(256) void prep_kernel(
    const float* __restrict__ x,
    const float* __restrict__ Wq, const float* __restrict__ Wk,
    const float* __restrict__ Wv, const float* __restrict__ Wo,
    const float* __restrict__ bq, const float* __restrict__ bk,
    const float* __restrict__ bv,
    u16* __restrict__ xb,
    u16* __restrict__ Wqkvt, u16* __restrict__ Wot, float* __restrict__ bqkv)
{
    __shared__ float T[64][65];
    const int bid = blockIdx.x;
    if (bid < 4096) {
        // x -> bf16, 4 elems/thread (4096 blocks x 1024 elems)
        int i = bid * 256 + threadIdx.x;
        float4 f = ((const float4*)x)[i];
        u16* d = xb + (size_t)i * 4;
        d[0] = f2b(f.x); d[1] = f2b(f.y); d[2] = f2b(f.z); d[3] = f2b(f.w);
    } else if (bid < 4352) {
        int b2 = bid - 4096;
        transpose_tile(Wq, Wqkvt, 1024, 1024, 0, b2 & 15, b2 >> 4, T);
    } else if (bid < 4368) {
        transpose_tile(Wk, Wqkvt, 1024, 64, 1024, 0, bid - 4352, T);
    } else if (bid < 4384) {
        transpose_tile(Wv, Wqkvt, 1024, 64, 1088, 0, bid - 4368, T);
    } else if (bid < 4640) {
        int b2 = bid - 4384;
        transpose_tile(Wo, Wot, 1024, 1024, 0, b2 & 15, b2 >> 4, T);
    } else {
        for (int i = threadIdx.x; i < NQKV; i += 256)
            bqkv[i] = (i < 1024) ? bq[i] : (i < 1088 ? bk[i - 1024] : bv[i - 1088]);
    }
}

// ---------------------------------------------------------------------------
// 128x128 GEMM inner step: 8 ds_read_b128 + 16 MFMA (wave owns 64x64 = 4x4)
// ---------------------------------------------------------------------------
__device__ __forceinline__ void gemm_step128(
    const u16* __restrict__ As, const u16* __restrict__ Bs,
    int wm, int wn, int quad, int ln16, f32x4 (*acc)[4])
{
    short8 af[4], bf[4];
    #pragma unroll
    for (int mt = 0; mt < 4; ++mt)
        af[mt] = *(const short8*)&As[(((wm * 4 + mt) * 64) + quad * 16 + ln16) * 8];
    #pragma unroll
    for (int nt = 0; nt < 4; ++nt)
        bf[nt] = *(const short8*)&Bs[(((wn * 4 + nt) * 64) + quad * 16 + ln16) * 8];
    #pragma unroll
    for (int mt = 0; mt < 4; ++mt)
        #pragma unroll
        for (int nt = 0; nt < 4; ++nt)
            acc[mt][nt] = __builtin_amdgcn_mfma_f32_16x16x32_bf16(
                af[mt], bf[nt], acc[mt][nt], 0, 0, 0);
}

__device__ __forceinline__ void gemm_stage4(
    const u16* ag0, const u16* ag1, const u16* bg0, const u16* bg1,
    u16* al0, u16* al1, u16* bl0, u16* bl1)
{
    async_copy16(ag0, al0);
    async_copy16(ag1, al1);
    async_copy16(bg0, bl0);
    async_copy16(bg1, bl1);
}

// Counted-vmcnt 3-buffer 128x128 K-loop (T3/T4): 4 staging loads per tile,
// 2 tiles staged ahead (8 in flight); wait vmcnt(4) retires exactly the
// oldest tile's 4 loads before the barrier -> after the barrier tile k is
// collectively resident while the next tile's loads stay in flight. vmcnt
// reaches 0 only on the final iteration. K=1024, BK=32 -> 32 tiles = 3x10+2.
#define STAGE128(KOFS, I)                                                     \
    gemm_stage4(ag0 + (KOFS), ag1 + (KOFS), bg0 + (KOFS), bg1 + (KOFS),       \
                aLo##I, aHi##I, bLo##I, bHi##I)

#define GEMM128_PIPE_LOOP()                                                   \
    STAGE128(0, 0);                                                           \
    STAGE128(32, 1);                                                          \
    for (int k = 0; k < 30; k += 3) {                                         \
        const int kb = k * 32;                                                \
        asm volatile("s_waitcnt vmcnt(4)" ::: "memory");                      \
        __builtin_amdgcn_s_barrier();                                         \
        STAGE128(kb + 64, 2);                                                 \
        gemm_step128(AsC[0], BsC[0], wm, wn, quad, ln16, acc);                \
        asm volatile("s_waitcnt vmcnt(4)" ::: "memory");                      \
        __builtin_amdgcn_s_barrier();                                         \
        STAGE128(kb + 96, 0);                                                 \
        gemm_step128(AsC[1], BsC[1], wm, wn, quad, ln16, acc);                \
        asm volatile("s_waitcnt vmcnt(4)" ::: "memory");                      \
        __builtin_amdgcn_s_barrier();                                         \
        STAGE128(kb + 128, 1);                                                \
        gemm_step128(AsC[2], BsC[2], wm, wn, quad, ln16, acc);                \
    }                                                                         \
    asm volatile("s_waitcnt vmcnt(4)" ::: "memory");                          \
    __builtin_amdgcn_s_barrier();                                             \
    gemm_step128(AsC[0], BsC[0], wm, wn, quad, ln16, acc);                    \
    asm volatile("s_waitcnt vmcnt(0)" ::: "memory");                          \
    __builtin_amdgcn_s_barrier();                                             \
    gemm_step128(AsC[1], BsC[1], wm, wn, quad, ln16, acc);

#define GEMM128_SETUP(Aptr, Btptr, Kdim)                                      \
    const int tid  = threadIdx.x;                                             \
    const int wave = tid >> 6, lane = tid & 63;                               \
    const int ln16 = lane & 15, quad = lane >> 4;                             \
    const int wm = wave >> 1, wn = wave & 1;                                  \
    const int m0 = blockIdx.y * 128, n0 = blockIdx.x * 128;                   \
    const int c_row = (wave << 4) + ln16;                                     \
    const int c_k   = quad * 8;                                               \
    const u16* ag0 = &(Aptr) [(size_t)(m0 + c_row)       * (Kdim) + c_k];     \
    const u16* ag1 = &(Aptr) [(size_t)(m0 + 64 + c_row)  * (Kdim) + c_k];     \
    const u16* bg0 = &(Btptr)[(size_t)(n0 + c_row)       * (Kdim) + c_k];     \
    const u16* bg1 = &(Btptr)[(size_t)(n0 + 64 + c_row)  * (Kdim) + c_k];     \
    u16* aLo0 = &AsC[0][(size_t)wave * 512];                                  \
    u16* aLo1 = &AsC[1][(size_t)wave * 512];                                  \
    u16* aLo2 = &AsC[2][(size_t)wave * 512];                                  \
    u16* aHi0 = &AsC[0][(size_t)(wave + 4) * 512];                            \
    u16* aHi1 = &AsC[1][(size_t)(wave + 4) * 512];                            \
    u16* aHi2 = &AsC[2][(size_t)(wave + 4) * 512];                            \
    u16* bLo0 = &BsC[0][(size_t)wave * 512];                                  \
    u16* bLo1 = &BsC[1][(size_t)wave * 512];                                  \
    u16* bLo2 = &BsC[2][(size_t)wave * 512];                                  \
    u16* bHi0 = &BsC[0][(size_t)(wave + 4) * 512];                            \
    u16* bHi1 = &BsC[1][(size_t)(wave + 4) * 512];                            \
    u16* bHi2 = &BsC[2][(size_t)(wave + 4) * 512];                            \
    f32x4 acc[4][4];                                                          \
    _Pragma("unroll")                                                         \
    for (int i = 0; i < 4; ++i)                                               \
        _Pragma("unroll")                                                     \
        for (int j = 0; j < 4; ++j) acc[i][j] = (f32x4){0.f, 0.f, 0.f, 0.f};

// ---------------------------------------------------------------------------
// Fused qkv projection: 128x128 tile, BK=32, 4 waves (2x2, 64x64 each),
// counted-vmcnt 3-buffer pipeline. Epilogue (R1-verified): RoPE q (pre-scaled
// 0.125*log2e so flash uses exp2), RoPE k, transpose v.
// ---------------------------------------------------------------------------
__global__ __launch_bounds__(256) void gemm_qkv_kernel(
    const u16* __restrict__ A, const u16* __restrict__ Bt,
    const float* __restrict__ bias,
    u16* __restrict__ qb, u16* __restrict__ kb, u16* __restrict__ vT)
{
    __shared__ __align__(16) u16 AsC[3][128 * 32];   // 24 KB
    __shared__ __align__(16) u16 BsC[3][128 * 32];   // 24 KB
    GEMM128_SETUP(A, Bt, CDIM);

    GEMM128_PIPE_LOOP();

    // ---- bias ----
    #pragma unroll
    for (int mt = 0; mt < 4; ++mt)
        #pragma unroll
        for (int nt = 0; nt < 4; ++nt) {
            float bb = bias[n0 + wn * 64 + nt * 16 + ln16];
            #pragma unroll
            for (int r = 0; r < 4; ++r) acc[mt][nt][r] += bb;
        }

    const int col0 = n0 + wn * 64;   // head-aligned category base
    if (col0 < 1024) {
        // ---- q: rope + (1/8)*log2e scale (flash uses exp2) -> qb ----
        const int hh = col0 >> 6;
        #pragma unroll
        for (int nt = 0; nt < 2; ++nt) {
            int j = nt * 16 + ln16;
            float fr = exp2f(-0.41524101186092029f * (float)j);  // 10000^(-j/32)
            #pragma unroll
            for (int mt = 0; mt < 4; ++mt)
                #pragma unroll
                for (int r = 0; r < 4; ++r) {
                    int m = m0 + wm * 64 + mt * 16 + quad * 4 + r;
                    float sn, cs;
                    __sincosf((float)(m & (TSEQ - 1)) * fr, &sn, &cs);
                    float t1 = acc[mt][nt][r], t2 = acc[mt][nt + 2][r];
                    u16* o = qb + (size_t)m * CDIM + hh * 64 + j;
                    o[0]  = f2b(fmaf(t1, cs,  t2 * sn) * 0.18033688011112043f);
                    o[32] = f2b(fmaf(t1, sn, -t2 * cs) * 0.18033688011112043f);
                }
        }
    } else if (wn == 0) {
        // ---- k: rope -> kb[bt][64] ----
        #pragma unroll
        for (int nt = 0; nt < 2; ++nt) {
            int j = nt * 16 + ln16;
            float fr = exp2f(-0.41524101186092029f * (float)j);
            #pragma unroll
            for (int mt = 0; mt < 4; ++mt)
                #pragma unroll
                for (int r = 0; r < 4; ++r) {
                    int m = m0 + wm * 64 + mt * 16 + quad * 4 + r;
                    float sn, cs;
                    __sincosf((float)(m & (TSEQ - 1)) * fr, &sn, &cs);
                    float t1 = acc[mt][nt][r], t2 = acc[mt][nt + 2][r];
                    u16* o = kb + (size_t)m * HDIM + j;
                    o[0]  = f2b(fmaf(t1, cs,  t2 * sn));
                    o[32] = f2b(fmaf(t1, sn, -t2 * cs));
                }
        }
    } else {
        // ---- v: transpose -> vT[b][d][T] (4 consecutive rows = 8B store) ----
        #pragma unroll
        for (int nt = 0; nt < 4; ++nt) {
            int d = nt * 16 + ln16;
            #pragma unroll
            for (int mt = 0; mt < 4; ++mt) {
                int mr = m0 + wm * 64 + mt * 16 + quad * 4;
                int b  = mr >> 11, tq = mr & (TSEQ - 1);
                uint2 val;
                val.x = pack2(acc[mt][nt][0], acc[mt][nt][1]);
                val.y = pack2(acc[mt][nt][2], acc[mt][nt][3]);
                *(uint2*)&vT[(size_t)(b * HDIM + d) * TSEQ + tq] = val;
            }
        }
    }
}

// ---------------------------------------------------------------------------
// Output projection: Y fp32 = A(bf16) @ Bt(bf16)^T + bias. 128x128 tile,
// BK=32, 4 waves (2x2), counted-vmcnt 3-buffer pipeline.
// ---------------------------------------------------------------------------
__global__ __launch_bounds__(256) void gemm_mfma_kernel(
    const u16* __restrict__ A, const u16* __restrict__ Bt,
    const float* __restrict__ bias, float* __restrict__ Y,
    int M, int N, int K)
{
    __shared__ __align__(16) u16 AsC[3][128 * 32];   // 24 KB
    __shared__ __align__(16) u16 BsC[3][128 * 32];   // 24 KB
    GEMM128_SETUP(A, Bt, K);

    GEMM128_PIPE_LOOP();

    #pragma unroll
    for (int mt = 0; mt < 4; ++mt)
        #pragma unroll
        for (int nt = 0; nt < 4; ++nt) {
            int n = n0 + wn * 64 + nt * 16 + ln16;
            float bb = bias[n];
            #pragma unroll
            for (int r = 0; r < 4; ++r) {
                int m = m0 + wm * 64 + mt * 16 + quad * 4 + r;
                Y[(size_t)m * N + n] = acc[mt][nt][r] + bb;
            }
        }
}

// ---------------------------------------------------------------------------
// Flash attention — SWAPPED QK^T, P fully in registers (no Ps LDS buffer):
// sv[t] = mfma(K_frag, Q_frag) gives S^T with lane layout
//   kv = t*16 + quad*4 + r,  q = ln16   (A: m=lane&15; B: n=lane&15;
//   C: m=quad*4+r, n=ln16 — all three verified by the prior QK^T/mask code).
// The SAME LDS reads serve as swapped operands (K slice matches the A-frag
// spec, Q slice matches the B-frag spec). P is truncated-packed into 8 u32
// (p01/p23[t] = bf16 pairs kv+0/1, +2/3) and redistributed with 16 __shfl +
// 8 selects: dest quad d, kk2-half word w pulls p_{w&1}[(d>>1)+2*kk2] from
// lane (2*(d&1)+(w>>1))*16+ln16 — giving the PV A-frag (q=ln16,
// k=quad*8+j) directly in registers.  Replaces 16 ds_write_b16 +
// 2 ds_read_b128 per tile and deletes the 9KB Ps buffer: LDS 49->40KB =
// 4 blocks/CU (16 waves, was 12). Values bit-identical (same exp2, same
// truncation, same MFMA order). Row-sum still via ones-column MFMA on the
// same pf. Balanced block->qt map (R10, +1us) kept. q pre-scaled by
// 0.125*log2e -> e = exp2(s).
// ---------------------------------------------------------------------------
__device__ __forceinline__ void flash_stage_kv(
    const u16* __restrict__ kb, const u16* __restrict__ vT,
    int b, int kt, u16* __restrict__ Ksb, u16* __restrict__ Vsb,
    const int* row_c, const int* off_c, int c0)
{
    const size_t kt0 = (size_t)(b * TSEQ + kt * 64);
    #pragma unroll
    for (int hf = 0; hf < 2; ++hf) {
        int cc = c0 + hf * 256;
        async_copy16(kb + (kt0 + row_c[hf]) * HDIM + off_c[hf], Ksb + cc * 8);
        async_copy16(vT + (size_t)(b * HDIM + row_c[hf]) * TSEQ + kt * 64 + off_c[hf],
                     Vsb + cc * 8);
    }
}

__device__ __forceinline__ u32 packtrunc2(float lo, float hi) {
    // truncated bf16 pair: low word = bits(lo)>>16, high word = bits(hi)&ffff0000
    return (__float_as_uint(lo) >> 16) | (__float_as_uint(hi) & 0xffff0000u);
}

__device__ __forceinline__ void flash_tile(
    const u16* __restrict__ Ksb, const u16* __restrict__ Vsb,
    const u16* __restrict__ Qs,
    int wave, int ln16, int quad, bool diag,
    f32x4* lacc, f32x4* oacc)
{
    // ---- S^T = K.Q^T (swapped operands; same LDS reads as before) ----
    f32x4 sv[4];
    #pragma unroll
    for (int t = 0; t < 4; ++t) sv[t] = (f32x4){0.f, 0.f, 0.f, 0.f};
    #pragma unroll
    for (int kk2 = 0; kk2 < 2; ++kk2) {
        short8 qf = *(const short8*)&Qs[(wave * 128 + kk2 * 64 + quad * 16 + ln16) * 8];
        #pragma unroll
        for (int t = 0; t < 4; ++t) {
            short8 kf = *(const short8*)&Ksb[(t * 128 + kk2 * 64 + quad * 16 + ln16) * 8];
            sv[t] = __builtin_amdgcn_mfma_f32_16x16x32_bf16(kf, qf, sv[t], 0, 0, 0);
        }
    }

    // ---- e = exp2(s') (0 if masked); truncate-pack to bf16 pairs ----
    // lane holds S^T[kv = t*16+quad*4+r][q = ln16]
    u32 p01[4], p23[4];
    if (diag) {
        const int qrow = wave * 16 + ln16;
        #pragma unroll
        for (int t = 0; t < 4; ++t) {
            float e[4];
            #pragma unroll
            for (int r = 0; r < 4; ++r) {
                int key = t * 16 + quad * 4 + r;
                e[r] = (key > qrow) ? 0.f : exp2f(sv[t][r]);
            }
            p01[t] = packtrunc2(e[0], e[1]);
            p23[t] = packtrunc2(e[2], e[3]);
        }
    } else {
        #pragma unroll
        for (int t = 0; t < 4; ++t) {
            float e0 = exp2f(sv[t][0]), e1 = exp2f(sv[t][1]);
            float e2 = exp2f(sv[t][2]), e3 = exp2f(sv[t][3]);
            p01[t] = packtrunc2(e0, e1);
            p23[t] = packtrunc2(e2, e3);
        }
    }

    // ---- redistribute P to PV A-frag layout (16 shfl + 8 selects) ----
    const int s0 = ((quad & 1) << 5) + ln16;   // lane a*16+ln16, a=2*(quad&1)
    const int s1 = s0 + 16;                     // lane (a+1)*16+ln16
    const bool g = (quad >> 1) != 0;            // selects t = (quad>>1)+2*kk2

    const short8 ones = {0x3F80, 0x3F80, 0x3F80, 0x3F80,
                         0x3F80, 0x3F80, 0x3F80, 0x3F80};   // bf16 1.0

    #pragma unroll
    for (int kk2 = 0; kk2 < 2; ++kk2) {
        u32 a01_0 = (u32)__shfl((int)p01[2 * kk2],     s0);
        u32 a01_1 = (u32)__shfl((int)p01[2 * kk2 + 1], s0);
        u32 a23_0 = (u32)__shfl((int)p23[2 * kk2],     s0);
        u32 a23_1 = (u32)__shfl((int)p23[2 * kk2 + 1], s0);
        u32 b01_0 = (u32)__shfl((int)p01[2 * kk2],     s1);
        u32 b01_1 = (u32)__shfl((int)p01[2 * kk2 + 1], s1);
        u32 b23_0 = (u32)__shfl((int)p23[2 * kk2],     s1);
        u32 b23_1 = (u32)__shfl((int)p23[2 * kk2 + 1], s1);
        union { u32 u[4]; short8 s; } pf;
        pf.u[0] = g ? a01_1 : a01_0;   // kv = base+0,1
        pf.u[1] = g ? a23_1 : a23_0;   // kv = base+2,3
        pf.u[2] = g ? b01_1 : b01_0;   // kv = base+4,5
        pf.u[3] = g ? b23_1 : b23_0;   // kv = base+6,7

        // ---- O += P.V ; denominator via ones-column MFMA on same pf ----
        *lacc = __builtin_amdgcn_mfma_f32_16x16x32_bf16(pf.s, ones, *lacc, 0, 0, 0);
        #pragma unroll
        for (int t = 0; t < 4; ++t) {
            short8 vf = *(const short8*)&Vsb[(t * 128 + kk2 * 64 + quad * 16 + ln16) * 8];
            oacc[t] = __builtin_amdgcn_mfma_f32_16x16x32_bf16(pf.s, vf, oacc[t], 0, 0, 0);
        }
    }
}

__global__ __launch_bounds__(256, 4) void flash_mfma_kernel(
    const u16* __restrict__ qb, const u16* __restrict__ kb,
    const u16* __restrict__ vT, u16* __restrict__ o)
{
    const int id  = blockIdx.x;
    const int rr  = id >> 8;          // colocation round (blocks c,c+256,... share a CU)
    const int c   = id & 255;
    const int g   = c >> 5;           // 0..7
    const int hb  = c & 31;
    // balanced map: per-CU iter sum = (32-g)+(17+g)+(16-g)+(1+g) = 66 for all g
    const int qt  = (rr == 0) ? 31 - g : (rr == 1) ? 16 + g : (rr == 2) ? 15 - g : g;
    const int h   = hb >> 1;
    const int b   = hb & 1;
    __shared__ __align__(16) u16 Qs [512 * 8];       // 8 KB
    __shared__ __align__(16) u16 Ks0[512 * 8];       // 8 KB  (double buffer)
    __shared__ __align__(16) u16 Ks1[512 * 8];       // 8 KB
    __shared__ __align__(16) u16 Vs0[512 * 8];       // 8 KB
    __shared__ __align__(16) u16 Vs1[512 * 8];       // 8 KB
    // (no Ps buffer — P lives in registers)  total 40 KB -> 4 blocks/CU

    const int tid  = threadIdx.x;
    const int wave = tid >> 6, lane = tid & 63;
    const int ln16 = lane & 15, quad = lane >> 4;

    const int c0 = tid;
    int row_c[2], off_c[2];
    #pragma unroll
    for (int hf = 0; hf < 2; ++hf) {
        int cc = c0 + hf * 256;
        row_c[hf] = ((cc >> 7) << 4) | (cc & 15);
        off_c[hf] = ((cc >> 6) & 1) * 32 + ((cc >> 4) & 3) * 8;
    }

    // ---- stage Q + K/V tile 0 ----
    #pragma unroll
    for (int hf = 0; hf < 2; ++hf)
        async_copy16(
            qb + (size_t)(b * TSEQ + qt * 64 + row_c[hf]) * CDIM + h * HDIM + off_c[hf],
            Qs + (c0 + hf * 256) * 8);
    flash_stage_kv(kb, vT, b, 0, Ks0, Vs0, row_c, off_c, c0);

    f32x4 lacc = (f32x4){0.f, 0.f, 0.f, 0.f};
    f32x4 oacc[4];
    #pragma unroll
    for (int t = 0; t < 4; ++t) oacc[t] = (f32x4){0.f, 0.f, 0.f, 0.f};

    int kt = 0;
    while (true) {
        __syncthreads();    // buf0 for kt ready; all waves done reading buf1
        if (kt < qt) flash_stage_kv(kb, vT, b, kt + 1, Ks1, Vs1, row_c, off_c, c0);
        flash_tile(Ks0, Vs0, Qs, wave, ln16, quad, kt == qt, &lacc, oacc);
        if (++kt > qt) break;
        __syncthreads();    // buf1 for kt ready; all waves done reading buf0
        if (kt < qt) flash_stage_kv(kb, vT, b, kt + 1, Ks0, Vs0, row_c, off_c, c0);
        flash_tile(Ks1, Vs1, Qs, wave, ln16, quad, kt == qt, &lacc, oacc);
        if (++kt > qt) break;
    }

    // ---- epilogue: denominators already fully reduced in lacc ----
    float inv[4];
    #pragma unroll
    for (int r = 0; r < 4; ++r) inv[r] = 1.0f / lacc[r];
    #pragma unroll
    for (int t = 0; t < 4; ++t) {
        #pragma unroll
        for (int r = 0; r < 4; ++r) {
            int row = qt * 64 + wave * 16 + quad * 4 + r;
            int d   = t * 16 + ln16;
            o[(size_t)(b * TSEQ + row) * CDIM + h * HDIM + d] = f2b(oacc[t][r] * inv[r]);
        }
    }
}

// ---------------------------------------------------------------------------
extern "C" void kernel_launch(void* const* d_in, const int* in_sizes, int n_in,
                              void* d_out, int out_size, void* d_ws, size_t ws_size,
                              hipStream_t stream)
{
    const float* x  = (const float*)d_in[0];
    const float* Wq = (const float*)d_in[1];
    const float* bq = (const float*)d_in[2];
    const float* Wk = (const float*)d_in[3];
    const float* bk = (const float*)d_in[4];
    const float* Wv = (const float*)d_in[5];
    const float* bv = (const float*)d_in[6];
    const float* Wo = (const float*)d_in[7];
    const float* bo = (const float*)d_in[8];
    float* out = (float*)d_out;

    const size_t MB = 1u << 20;
    char* w = (char*)d_ws;
    u16*   xb   = (u16*)(w);                   //  8 MB [BT][1024] bf16
    u16*   aob  = (u16*)(w);                   //  alias: xb dead after qkv GEMM
    u16*   qb   = (u16*)(w + 8 * MB);          //  8 MB [BT][1024] rope'd, scaled
    u16*   kb   = (u16*)(w + 16 * MB);         //  0.5 MB [BT][64]
    u16*   vT   = (u16*)(w + 16 * MB + 512 * 1024);   // 0.5 MB [B][64][T]
    u16*   Wqkvt= (u16*)(w + 17 * MB);         //  2.25 MB [1152][1024]
    u16*   Wot  = (u16*)(w + 20 * MB);         //  2 MB
    float* bqkv = (float*)(w + 22 * MB);       //  4.5 KB

    // 1) x-cast + weight transposes + bias concat, one launch
    prep_kernel<<<dim3(4641), dim3(256), 0, stream>>>(
        x, Wq, Wk, Wv, Wo, bq, bk, bv, xb, Wqkvt, Wot, bqkv);
    // 2) fused qkv projection + rope + v-transpose -> qb, kb, vT (bf16)
    gemm_qkv_kernel<<<dim3(NQKV / 128, BT / 128), dim3(256), 0, stream>>>(
        xb, Wqkvt, bqkv, qb, kb, vT);
    // 3) flash attention -> aob (overwrites dead xb)
    flash_mfma_kernel<<<dim3(32 * NHEAD * BSZ), dim3(256), 0, stream>>>(
        qb, kb, vT, aob);
    // 4) output projection
    gemm_mfma_kernel<<<dim3(CDIM / 128, BT / 128), dim3(256), 0, stream>>>(
        aob, Wot, bo, out, BT, CDIM, CDIM);
}